// Round 8
// baseline (421.372 us; speedup 1.0000x reference)
//
#include <hip/hip_runtime.h>
#include <stdint.h>

// Problem constants
#define B_ 4
#define S_ 2048
#define E_ 1024
#define H_ 16
#define HD_ 64

typedef __attribute__((ext_vector_type(8))) short bf16x8;   // 8 bf16 = 4 VGPRs (MFMA A/B frag)
typedef __attribute__((ext_vector_type(4))) float f32x4;    // MFMA C/D frag

__device__ __forceinline__ ushort f2b(float f) {
    union { float f; uint32_t u; } c; c.f = f;
    return (ushort)((c.u + 0x8000u) >> 16);   // round-to-nearest (ties up)
}

// truncating pack: two f32 -> {bf16_trunc(a) lo, bf16_trunc(b) hi} in ONE v_perm.
// Used ONLY for P in attn: the same truncated P feeds numerator (PV) and
// denominator (ones-MFMA), so the <=2^-8 truncation bias cancels in the ratio.
__device__ __forceinline__ uint32_t pkbf_t(float a, float b) {
    union { float f; uint32_t u; } ca, cb; ca.f = a; cb.f = b;
#if __has_builtin(__builtin_amdgcn_perm)
    return __builtin_amdgcn_perm(cb.u, ca.u, 0x07060302u);
#else
    return (ca.u >> 16) | (cb.u & 0xFFFF0000u);
#endif
}

// all-ones iff bit `pos` of wn is set (1 op: v_bfe_i32)
__device__ __forceinline__ uint32_t keepmask(uint32_t wn, int pos) {
#if __has_builtin(__builtin_amdgcn_sbfe)
    return (uint32_t)__builtin_amdgcn_sbfe((int)wn, pos, 1);
#else
    return (uint32_t)(((int32_t)(wn << (31 - pos))) >> 31);
#endif
}

#if __has_builtin(__builtin_amdgcn_exp2f)
#define EXP2(x) __builtin_amdgcn_exp2f(x)
#else
#define EXP2(x) exp2f(x)
#endif

// async global->LDS, 16B per lane; LDS dest = wave-uniform base + lane*16,
// global src = PER-LANE address (gather) -> source-side permutations are free.
__device__ __forceinline__ void gl2lds16(const ushort* g, const ushort* l) {
    __builtin_amdgcn_global_load_lds(
        (const __attribute__((address_space(1))) unsigned int*)g,
        (__attribute__((address_space(3))) unsigned int*)l,
        16, 0, 0);
}

// ---------------------------------------------------------------- fused converts
__global__ __launch_bounds__(256) void cvt_all(
    const float* __restrict__ x, const float* __restrict__ wq, const float* __restrict__ wo,
    ushort* __restrict__ xb, ushort* __restrict__ wqb, ushort* __restrict__ wob) {
    int i = blockIdx.x * 256 + threadIdx.x;
    const float* src; ushort* dst; int off;
    if (i < 2097152)      { src = x;  dst = xb;  off = i; }
    else if (i < 2883584) { src = wq; dst = wqb; off = i - 2097152; }
    else                  { src = wo; dst = wob; off = i - 2883584; }
    float4 f = ((const float4*)src)[off];
    ushort4 o;
    o.x = f2b(f.x); o.y = f2b(f.y); o.z = f2b(f.z); o.w = f2b(f.w);
    ((ushort4*)dst)[off] = o;
}

// mask [B,S,S] int32 (0/1) -> bit-packed, kt-major:
// mb[((b*32 + kt)*2048 + q)*2 + w] bit c = mask[b][q][kt*64 + w*32 + c]
__global__ __launch_bounds__(256) void pack_mask(const int* __restrict__ mask,
                                                 uint32_t* __restrict__ mb) {
    int i = blockIdx.x * 256 + threadIdx.x;   // 16777216 threads
    unsigned long long bal = __ballot(mask[i] == 1);
    int lane = threadIdx.x & 63;
    if (lane < 2) {
        int b = i >> 22, q = (i >> 11) & 2047, c = i & 2047;
        int kt = c >> 6;
        mb[((uint64_t)(b * 32 + kt) * 2048 + q) * 2 + lane] =
            (lane == 0) ? (uint32_t)bal : (uint32_t)(bal >> 32);
    }
}

// ---------------------------------------------------------------- GEMM core (dist-2 ring)
template <int KD>
__device__ __forceinline__ void gemm_bt_core(
    const ushort* __restrict__ A, const ushort* __restrict__ Bm,
    int m0, int n0, ushort* L, f32x4 (&acc)[4][4])
{
    constexpr int NST = KD / 32;
    const int tid  = threadIdx.x;
    const int lane = tid & 63;
    const int wave = tid >> 6;
    const int wm = wave >> 1, wn = wave & 1;
    const int fr = lane & 15;
    const int fk = (lane >> 4) * 8;
    const int lrow = lane >> 2;
    const int lk   = (lane & 3) * 8;

    const f32x4 fz = {0.f, 0.f, 0.f, 0.f};
#pragma unroll
    for (int i = 0; i < 4; ++i)
#pragma unroll
        for (int j = 0; j < 4; ++j) acc[i][j] = fz;

    ushort* s0 = L;
    ushort* s1 = L + 8192;
    ushort* s2 = L + 16384;

    const uint64_t arow = (uint64_t)(m0 + lrow) * KD + lk;
    const uint64_t brow = (uint64_t)(n0 + lrow) * KD + lk;

#define GEMM_STAGE(k0, slot)                                                     \
    {                                                                            \
        _Pragma("unroll")                                                        \
        for (int t = 0; t < 2; ++t) {                                            \
            const int r0 = t * 64 + wave * 16;                                   \
            gl2lds16(&A [arow + (uint64_t)r0 * KD + (k0)], &(slot)[r0 * 32]);    \
            gl2lds16(&Bm[brow + (uint64_t)r0 * KD + (k0)], &(slot)[4096 + r0 * 32]); \
        }                                                                        \
    }

    GEMM_STAGE(0, s0);
    GEMM_STAGE(32, s1);
    asm volatile("s_waitcnt vmcnt(4)" ::: "memory");
    __builtin_amdgcn_s_barrier();
    __builtin_amdgcn_sched_barrier(0);

    ushort* cur = s0; ushort* nxt = s1; ushort* tgt = s2;

    for (int kt = 0; kt < NST; ++kt) {
        if (kt < NST - 2) GEMM_STAGE((kt + 2) * 32, tgt);

        bf16x8 af[4], bfr[4];
#pragma unroll
        for (int i = 0; i < 4; ++i)
            af[i] = *(const bf16x8*)&cur[(wm * 64 + i * 16 + fr) * 32 + fk];
#pragma unroll
        for (int j = 0; j < 4; ++j)
            bfr[j] = *(const bf16x8*)&cur[4096 + (wn * 64 + j * 16 + fr) * 32 + fk];
        __builtin_amdgcn_s_setprio(1);
#pragma unroll
        for (int i = 0; i < 4; ++i)
#pragma unroll
            for (int j = 0; j < 4; ++j)
                acc[i][j] = __builtin_amdgcn_mfma_f32_16x16x32_bf16(af[i], bfr[j], acc[i][j], 0, 0, 0);
        __builtin_amdgcn_s_setprio(0);

        if (kt < NST - 2) {
            asm volatile("s_waitcnt vmcnt(4)" ::: "memory");
        } else {
            asm volatile("s_waitcnt vmcnt(0)" ::: "memory");
        }
        __builtin_amdgcn_s_barrier();
        __builtin_amdgcn_sched_barrier(0);

        ushort* o = cur; cur = nxt; nxt = tgt; tgt = o;
    }
#undef GEMM_STAGE
}

// ---------------------------------------------------------------- QKV GEMM
__global__ __launch_bounds__(256) void qkv_gemm(
    const ushort* __restrict__ xb, const ushort* __restrict__ wb,
    const float* __restrict__ bqkv,
    ushort* __restrict__ qo, ushort* __restrict__ ko, ushort* __restrict__ vto)
{
    __shared__ __align__(16) ushort L[24576];   // 48 KB ring
    f32x4 acc[4][4];
    const int lin = blockIdx.x;                  // 1536 = 8 * 192
    const int swz = (lin & 7) * 192 + (lin >> 3);
    const int m0 = (swz & 63) * 128;
    const int n0 = (swz >> 6) * 128;
    gemm_bt_core<1024>(xb, wb, m0, n0, L, acc);

    const int lane = threadIdx.x & 63, wave = threadIdx.x >> 6;
    const int wm = wave >> 1, wn = wave & 1;
    const int col = lane & 15, rg = lane >> 4;
    const float QSC = 0.125f * 1.4426950408889634f;
#pragma unroll
    for (int j = 0; j < 4; ++j) {
        const int n = n0 + wn * 64 + j * 16 + col;
        const int h = n / 192, f = n % 192;
        const float bias = bqkv[n];
#pragma unroll
        for (int i2 = 0; i2 < 4; ++i2) {
            const int mbase = m0 + wm * 64 + i2 * 16 + rg * 4;
            if (f < 128) {
#pragma unroll
                for (int v = 0; v < 4; ++v) {
                    const int m = mbase + v;
                    const int b = m >> 11, s = m & 2047;
                    const float val = acc[i2][j][v] + bias;
                    if (f < 64) qo[((uint64_t)(b * 16 + h) * 2048 + s) * 64 + f]        = f2b(val * QSC);
                    else        ko[((uint64_t)(b * 16 + h) * 2048 + s) * 64 + (f - 64)] = f2b(val);
                }
            } else {
                const int b = mbase >> 11, s = mbase & 2047;
                ushort4 pk;
                pk.x = f2b(acc[i2][j][0] + bias);
                pk.y = f2b(acc[i2][j][1] + bias);
                pk.z = f2b(acc[i2][j][2] + bias);
                pk.w = f2b(acc[i2][j][3] + bias);
                *(ushort4*)&vto[((uint64_t)(b * 16 + h) * 64 + (f - 128)) * 2048 + s] = pk;
            }
        }
    }
}

// ---------------------------------------------------------------- flash attention v12
// = v11 staging (3-slot dist-2 ring, 48 KB, vmcnt-counted; validated 93 us)
// + delayed-PV phase pipeline (T15): phase kt computes QK^T(kt) [MFMA] in the
//   SAME scheduling region as softmax(kt-1) [VALU] -- independent, so the
//   scheduler overlaps the pipes instead of serializing QKT->softmax->PV.
//   PV(kt-1) follows. The prefetch slot (kt+2)%3 == PV's slot (kt-1)%3, so a
//   bare mid-phase s_barrier precedes the gl2lds issue (cross-wave WAR).
//   Mask loads moved to phase-top => end-of-phase wait is vmcnt(4) (keeps only
//   this phase's 4 gl2lds in flight). Scores double-buffered scA/scB with
//   static renaming (2x-unrolled loop; rule #20).
__global__ __launch_bounds__(256, 3) void attn_kernel(
    const ushort* __restrict__ qa, const ushort* __restrict__ ka,
    const ushort* __restrict__ vta, const uint32_t* __restrict__ mbits,
    ushort* __restrict__ ctxo)
{
    __shared__ __align__(16) ushort LDSH[24576];   // 48 KB: 3 x (K 8KB + V 8KB)
    ushort* const Ks0 = LDSH;
    ushort* const Vt0 = LDSH + 4096;
    ushort* const Ks1 = LDSH + 8192;
    ushort* const Vt1 = LDSH + 12288;
    ushort* const Ks2 = LDSH + 16384;
    ushort* const Vt2 = LDSH + 20480;
    ushort* const CTX = LDSH;                      // epilogue stage (16KB, aliases slot0 K/V + slot1 K)

    const int bid = blockIdx.x;
    const int bh = (bid & 7) * 8 + (bid >> 7);
    const int qb = (bid >> 3) & 15;
    const int b = bh >> 4;
    const int tid = threadIdx.x, lane = tid & 63, wave = tid >> 6;
    const int col = lane & 15, rg = lane >> 4;

    const uint64_t bhoff = (uint64_t)bh * (S_ * 64);
    const ushort* qp = qa + bhoff + (uint64_t)qb * 128 * 64;
    const ushort* kp = ka + bhoff;
    const ushort* vp = vta + bhoff;                       // [64][2048]
    const uint32_t* mk0 = mbits + ((uint64_t)(b * 32) * 2048 + qb * 128 + wave * 32 + col) * 2;
    const uint32_t* mk1 = mk0 + 32;

    // staging geometry: 8 LDS rows / instruction; per-lane source gather
    const int lr = lane >> 3;
    const int usw = (lane & 7) ^ lr;
    const int r0s = wave * 16 + lr;
    const int r1s = r0s + 8;
    const int sg0 = (r0s & 32) | ((r0s & 12) << 1) | ((r0s & 16) >> 2) | (r0s & 3);
    const int sg1 = (r1s & 32) | ((r1s & 12) << 1) | ((r1s & 16) >> 2) | (r1s & 3);
    const int kb0 = sg0 * 64 + usw * 8;
    const int kb1 = sg1 * 64 + usw * 8;
    const int vb0 = r0s * 2048 + usw * 8;
    const int vb1 = r1s * 2048 + usw * 8;
    const int ldst0 = wave * 1024;
    const int ldst1 = ldst0 + 512;

    // Q fragments straight from global
    bf16x8 aq[2][2];
#pragma unroll
    for (int i = 0; i < 2; ++i)
#pragma unroll
        for (int k2 = 0; k2 < 2; ++k2)
            aq[i][k2] = *(const bf16x8*)&qp[(wave * 32 + i * 16 + col) * 64 + k2 * 32 + rg * 8];

    // prologue: masks [0],[1] then K/V [0],[1]; full drain once.
    uint2 m_a0 = *(const uint2*)mk0;
    uint2 m_a1 = *(const uint2*)mk1;
    uint2 m_b0 = *(const uint2*)(mk0 + 4096);
    uint2 m_b1 = *(const uint2*)(mk1 + 4096);
    uint2 m_c0, m_c1, m_d0, m_d1;
    gl2lds16(&kp[kb0], &Ks0[ldst0]);
    gl2lds16(&kp[kb1], &Ks0[ldst1]);
    gl2lds16(&vp[vb0], &Vt0[ldst0]);
    gl2lds16(&vp[vb1], &Vt0[ldst1]);
    gl2lds16(&kp[4096 + kb0], &Ks1[ldst0]);
    gl2lds16(&kp[4096 + kb1], &Ks1[ldst1]);
    gl2lds16(&vp[vb0 + 64], &Vt1[ldst0]);
    gl2lds16(&vp[vb1 + 64], &Vt1[ldst1]);
    asm volatile("s_waitcnt vmcnt(0)" ::: "memory");
    __builtin_amdgcn_s_barrier();
    __builtin_amdgcn_sched_barrier(0);

    const f32x4 fz = {0.f, 0.f, 0.f, 0.f};
    f32x4 acc[4][2];
#pragma unroll
    for (int dt = 0; dt < 4; ++dt)
#pragma unroll
        for (int i = 0; i < 2; ++i) acc[dt][i] = fz;
    f32x4 acc5[2] = {fz, fz};

    bf16x8 vone;
#pragma unroll
    for (int e = 0; e < 8; ++e) vone[e] = (short)0x3F80;

    int bpos[2][4];
#pragma unroll
    for (int p = 0; p < 2; ++p)
#pragma unroll
        for (int v = 0; v < 4; ++v) bpos[p][v] = rg * 8 + p * 4 + v;

    const int u0 = (rg ^ (col & 7)) << 3;

    f32x4 scA[2][4], scB[2][4];
    bf16x8 bp[2][2];

#define QKT_STEP(PK, SCOUT)                                                    \
    _Pragma("unroll")                                                          \
    for (int j = 0; j < 4; ++j) {                                              \
        bf16x8 bk0 = *(const bf16x8*)&(PK)[(j * 16 + col) * 64 + u0];          \
        bf16x8 bk1 = *(const bf16x8*)&(PK)[(j * 16 + col) * 64 + (u0 ^ 32)];   \
        _Pragma("unroll")                                                      \
        for (int i = 0; i < 2; ++i) {                                          \
            f32x4 z = __builtin_amdgcn_mfma_f32_16x16x32_bf16(bk0, aq[i][0], fz, 0, 0, 0); \
            SCOUT[i][j] = __builtin_amdgcn_mfma_f32_16x16x32_bf16(bk1, aq[i][1], z, 0, 0, 0); \
        }                                                                      \
    }

#define SOFTMAX_STEP(SCIN)                                                     \
    _Pragma("unroll")                                                          \
    for (int i = 0; i < 2; ++i) {                                              \
        const uint2 mw = i ? m_a1 : m_a0;                                      \
        const uint32_t wnx = ~mw.x, wny = ~mw.y;                               \
        union { uint32_t w[4]; bf16x8 v; } p0, p1;                             \
        _Pragma("unroll")                                                      \
        for (int j = 0; j < 4; ++j) {                                          \
            const uint32_t wn = (j & 2) ? wny : wnx;                           \
            const int p = j & 1;                                               \
            float pe[4];                                                       \
            _Pragma("unroll")                                                  \
            for (int v = 0; v < 4; ++v) {                                      \
                union { float f; uint32_t u; } cu;                             \
                cu.f = SCIN[i][j][v];                                          \
                cu.u &= keepmask(wn, bpos[p][v]);                              \
                pe[v] = EXP2(cu.f);                                            \
            }                                                                  \
            const uint32_t lo = pkbf_t(pe[0], pe[1]);                          \
            const uint32_t hi = pkbf_t(pe[2], pe[3]);                          \
            if (j < 2) { p0.w[p * 2] = lo; p0.w[p * 2 + 1] = hi; }             \
            else       { p1.w[p * 2] = lo; p1.w[p * 2 + 1] = hi; }             \
        }                                                                      \
        bp[i][0] = p0.v;                                                       \
        bp[i][1] = p1.v;                                                       \
    }

#define PV_STEP(PVP)                                                           \
    _Pragma("unroll")                                                          \
    for (int i = 0; i < 2; ++i) {                                              \
        acc5[i] = __builtin_amdgcn_mfma_f32_16x16x32_bf16(vone, bp[i][0], acc5[i], 0, 0, 0); \
        acc5[i] = __builtin_amdgcn_mfma_f32_16x16x32_bf16(vone, bp[i][1], acc5[i], 0, 0, 0); \
    }                                                                          \
    _Pragma("unroll")                                                          \
    for (int dt = 0; dt < 4; ++dt) {                                           \
        bf16x8 av0 = *(const bf16x8*)&(PVP)[(dt * 16 + col) * 64 + u0];        \
        bf16x8 av1 = *(const bf16x8*)&(PVP)[(dt * 16 + col) * 64 + (u0 ^ 32)]; \
        _Pragma("unroll")                                                      \
        for (int i = 0; i < 2; ++i) {                                          \
            acc[dt][i] = __builtin_amdgcn_mfma_f32_16x16x32_bf16(av0, bp[i][0], acc[dt][i], 0, 0, 0); \
            acc[dt][i] = __builtin_amdgcn_mfma_f32_16x16x32_bf16(av1, bp[i][1], acc[dt][i], 0, 0, 0); \
        }                                                                      \
    }

    // phase 0 (peeled): load mask[2]; issue K/V[2] (slot2 virgin, no WAR);
    // QK^T(0) -> scA. End: vmcnt(4) keeps the 4 gl2lds, drains mask[2].
    m_c0 = *(const uint2*)(mk0 + (uint64_t)2 * 4096);
    m_c1 = *(const uint2*)(mk1 + (uint64_t)2 * 4096);
    gl2lds16(&kp[2 * 4096 + kb0], &Ks2[ldst0]);
    gl2lds16(&kp[2 * 4096 + kb1], &Ks2[ldst1]);
    gl2lds16(&vp[vb0 + 2 * 64], &Vt2[ldst0]);
    gl2lds16(&vp[vb1 + 2 * 64], &Vt2[ldst1]);
    QKT_STEP(Ks0, scA)
    asm volatile("s_waitcnt vmcnt(4)" ::: "memory");
    __builtin_amdgcn_s_barrier();
    __builtin_amdgcn_sched_barrier(0);

    // rotating slot roles entering PHASE(kt): A = kt%3 (K read by QK^T(kt)),
    // C = (kt+2)%3 == (kt-1)%3 (V read by PV(kt-1) AND the prefetch target).
    ushort* pKA = Ks1; ushort* pKB = Ks2; ushort* pKC = Ks0;
    ushort* pVA = Vt1; ushort* pVB = Vt2; ushort* pVC = Vt0;

#define ATTN_PHASE(KT, SCIN, SCOUT)                                            \
    {                                                                          \
        const int kt_ = (KT);                                                  \
        if (kt_ <= 29) {                                                       \
            m_d0 = *(const uint2*)(mk0 + (uint64_t)(kt_ + 2) * 4096);          \
            m_d1 = *(const uint2*)(mk1 + (uint64_t)(kt_ + 2) * 4096);          \
        }                                                                      \
        __builtin_amdgcn_s_setprio(1);                                         \
        QKT_STEP(pKA, SCOUT)                                                   \
        __builtin_amdgcn_s_setprio(0);                                         \
        SOFTMAX_STEP(SCIN)                                                     \
        __builtin_amdgcn_s_setprio(1);                                         \
        PV_STEP(pVC)                                                           \
        __builtin_amdgcn_s_setprio(0);                                         \
        __builtin_amdgcn_s_barrier();     /* PV reads of slot C done (WAR) */  \
        if (kt_ <= 29) {                                                       \
            const int ko_ = (kt_ + 2) * 4096;                                  \
            gl2lds16(&kp[ko_ + kb0], &pKC[ldst0]);                             \
            gl2lds16(&kp[ko_ + kb1], &pKC[ldst1]);                             \
            gl2lds16(&vp[vb0 + (kt_ + 2) * 64], &pVC[ldst0]);                  \
            gl2lds16(&vp[vb1 + (kt_ + 2) * 64], &pVC[ldst1]);                  \
            asm volatile("s_waitcnt vmcnt(4)" ::: "memory");                   \
        } else {                                                               \
            asm volatile("s_waitcnt vmcnt(0)" ::: "memory");                   \
        }                                                                      \
        __builtin_amdgcn_s_barrier();                                          \
        __builtin_amdgcn_sched_barrier(0);                                     \
        m_a0 = m_b0; m_a1 = m_b1; m_b0 = m_c0; m_b1 = m_c1;                    \
        m_c0 = m_d0; m_c1 = m_d1;                                              \
        { ushort* t_ = pKA; pKA = pKB; pKB = pKC; pKC = t_; }                  \
        { ushort* t_ = pVA; pVA = pVB; pVB = pVC; pVC = t_; }                  \
    }

    for (int k2 = 0; k2 < 15; ++k2) {
        ATTN_PHASE(2 * k2 + 1, scA, scB)
        ATTN_PHASE(2 * k2 + 2, scB, scA)
    }
    ATTN_PHASE(31, scA, scB)

    // final: softmax(31) + PV(31) (V slot 31%3 = 1 = pVC after rotation)
    SOFTMAX_STEP(scB)
    PV_STEP(pVC)

#undef ATTN_PHASE
#undef QKT_STEP
#undef SOFTMAX_STEP
#undef PV_STEP

    // 1/l per q=col lane
    float linv[2];
#pragma unroll
    for (int i = 0; i < 2; ++i) linv[i] = 1.0f / acc5[i][0];

    // transpose ctx^T back through CTX (swizzled; ushort 0..8191, disjoint from
    // Vt1 = ushort 12288.. read by the final PV above) for coalesced store.
#pragma unroll
    for (int dt = 0; dt < 4; ++dt)
#pragma unroll
        for (int i = 0; i < 2; ++i) {
            const int q = wave * 32 + i * 16 + col;
            const int d = dt * 16 + rg * 4;
            const int gg = (d >> 3) ^ (q & 7);
            ushort4 pk;
            pk.x = f2b(acc[dt][i][0] * linv[i]);
            pk.y = f2b(acc[dt][i][1] * linv[i]);
            pk.z = f2b(acc[dt][i][2] * linv[i]);
            pk.w = f2b(acc[dt][i][3] * linv[i]);
            *(ushort4*)&CTX[q * 64 + gg * 8 + (d & 7)] = pk;
        }
    __syncthreads();
    const int h = bh & 15;
    const uint64_t obase = (uint64_t)(b * S_ + qb * 128) * E_ + (uint64_t)h * 64;
#pragma unroll
    for (int t4 = 0; t4 < 4; ++t4) {
        const int id = tid + t4 * 256;
        const int r = id >> 3, c8 = id & 7;
        *(bf16x8*)&ctxo[obase + (uint64_t)r * E_ + c8 * 8] =
            *(const bf16x8*)&CTX[r * 64 + ((c8 ^ (r & 7)) << 3)];
    }
}

// ---------------------------------------------------------------- output GEMM
__global__ __launch_bounds__(256) void out_gemm(
    const ushort* __restrict__ ctxb, const ushort* __restrict__ wob,
    const float* __restrict__ bo, float* __restrict__ out)
{
    __shared__ __align__(16) ushort L[24576];   // 48 KB ring
    f32x4 acc[4][4];
    const int lin = blockIdx.x;
    const int swz = (lin & 7) * 64 + (lin >> 3);
    const int m0 = (swz & 63) * 128;
    const int n0 = (swz >> 6) * 128;
    gemm_bt_core<1024>(ctxb, wob, m0, n0, L, acc);

    const int lane = threadIdx.x & 63, wave = threadIdx.x >> 6;
    const int wm = wave >> 1, wn = wave & 1;
    const int col = lane & 15, rg = lane >> 4;
#pragma unroll
    for (int j = 0; j < 4; ++j) {
        const int n = n0 + wn * 64 + j * 16 + col;
        const float bias = bo[n];
#pragma unroll
        for (int i2 = 0; i2 < 4; ++i2) {
            const int mb2 = m0 + wm * 64 + i2 * 16 + rg * 4;
#pragma unroll
            for (int v = 0; v < 4; ++v)
                out[(uint64_t)(mb2 + v) * 1024 + n] = acc[i2][j][v] + bias;
        }
    }
}

// ---------------------------------------------------------------- launch
extern "C" void kernel_launch(void* const* d_in, const int* in_sizes, int n_in,
                              void* d_out, int out_size, void* d_ws, size_t ws_size,
                              hipStream_t stream)
{
    const float* x    = (const float*)d_in[0];
    const int*   mask = (const int*)d_in[1];
    const float* Wqkv = (const float*)d_in[2];
    const float* bqkv = (const float*)d_in[3];
    const float* Wo   = (const float*)d_in[4];
    const float* bo   = (const float*)d_in[5];
    float* out = (float*)d_out;

    char* p = (char*)d_ws;
    ushort* xb  = (ushort*)p; p += (size_t)8388608 * 2;   // x bf16 [8192][1024]
    ushort* wqb = (ushort*)p; p += (size_t)3145728 * 2;   // Wqkv bf16 [3072][1024]
    ushort* wob = (ushort*)p; p += (size_t)1048576 * 2;   // Wo bf16 [1024][1024]
    ushort* qo  = (ushort*)p; p += (size_t)8388608 * 2;   // Q bf16 (log2-domain prescale)
    ushort* ko  = (ushort*)p; p += (size_t)8388608 * 2;   // K bf16 [bh][s][64]
    ushort* vto = (ushort*)p; p += (size_t)8388608 * 2;   // V^T bf16 [bh][64][s]
    ushort* ctx = (ushort*)p; p += (size_t)8388608 * 2;   // ctx bf16 [8192][1024]
    uint32_t* mb = (uint32_t*)p;                          // packed mask bits (kt-major), 2 MB

    cvt_all<<<12288, 256, 0, stream>>>(x, Wqkv, Wo, xb, wqb, wob);
    pack_mask<<<65536, 256, 0, stream>>>(mask, mb);
    qkv_gemm<<<1536, 256, 0, stream>>>(xb, wqb, bqkv, qo, ko, vto);
    attn_kernel<<<1024, 256, 0, stream>>>(qo, ko, vto, mb, ctx);
    out_gemm<<<512, 256, 0, stream>>>(ctx, wob, bo, out);
}

// Round 9
// 360.883 us; speedup vs baseline: 1.1676x; 1.1676x over previous
//
#include <hip/hip_runtime.h>
#include <stdint.h>

// Problem constants
#define B_ 4
#define S_ 2048
#define E_ 1024
#define H_ 16
#define HD_ 64

typedef __attribute__((ext_vector_type(8))) short bf16x8;    // 8 bf16 = 4 VGPRs (MFMA A/B frag)
typedef __attribute__((ext_vector_type(4))) float f32x4;     // 16x16 MFMA C/D frag
typedef __attribute__((ext_vector_type(16))) float f32x16;   // 32x32 MFMA C/D frag

__device__ __forceinline__ ushort f2b(float f) {
    union { float f; uint32_t u; } c; c.f = f;
    return (ushort)((c.u + 0x8000u) >> 16);   // round-to-nearest (ties up)
}

// truncating pack: two f32 -> {bf16_trunc(a) lo, bf16_trunc(b) hi} in ONE v_perm.
// Used ONLY for P in attn: the same truncated P feeds numerator (PV) and
// denominator (ones-MFMA), so the <=2^-8 truncation bias cancels in the ratio.
__device__ __forceinline__ uint32_t pkbf_t(float a, float b) {
    union { float f; uint32_t u; } ca, cb; ca.f = a; cb.f = b;
#if __has_builtin(__builtin_amdgcn_perm)
    return __builtin_amdgcn_perm(cb.u, ca.u, 0x07060302u);
#else
    return (ca.u >> 16) | (cb.u & 0xFFFF0000u);
#endif
}

// all-ones iff bit `pos` of wn is set (1 op: v_bfe_i32)
__device__ __forceinline__ uint32_t keepmask(uint32_t wn, int pos) {
#if __has_builtin(__builtin_amdgcn_sbfe)
    return (uint32_t)__builtin_amdgcn_sbfe((int)wn, pos, 1);
#else
    return (uint32_t)(((int32_t)(wn << (31 - pos))) >> 31);
#endif
}

#if __has_builtin(__builtin_amdgcn_exp2f)
#define EXP2(x) __builtin_amdgcn_exp2f(x)
#else
#define EXP2(x) exp2f(x)
#endif

// async global->LDS, 16B per lane; LDS dest = wave-uniform base + lane*16,
// global src = PER-LANE address (gather) -> source-side permutations are free.
__device__ __forceinline__ void gl2lds16(const ushort* g, const ushort* l) {
    __builtin_amdgcn_global_load_lds(
        (const __attribute__((address_space(1))) unsigned int*)g,
        (__attribute__((address_space(3))) unsigned int*)l,
        16, 0, 0);
}

// ---------------------------------------------------------------- fused converts
__global__ __launch_bounds__(256) void cvt_all(
    const float* __restrict__ x, const float* __restrict__ wq, const float* __restrict__ wo,
    ushort* __restrict__ xb, ushort* __restrict__ wqb, ushort* __restrict__ wob) {
    int i = blockIdx.x * 256 + threadIdx.x;
    const float* src; ushort* dst; int off;
    if (i < 2097152)      { src = x;  dst = xb;  off = i; }
    else if (i < 2883584) { src = wq; dst = wqb; off = i - 2097152; }
    else                  { src = wo; dst = wob; off = i - 2883584; }
    float4 f = ((const float4*)src)[off];
    ushort4 o;
    o.x = f2b(f.x); o.y = f2b(f.y); o.z = f2b(f.z); o.w = f2b(f.w);
    ((ushort4*)dst)[off] = o;
}

// mask [B,S,S] int32 (0/1) -> bit-packed, kt-major:
// mb[((b*32 + kt)*2048 + q)*2 + w] bit c = mask[b][q][kt*64 + w*32 + c]
__global__ __launch_bounds__(256) void pack_mask(const int* __restrict__ mask,
                                                 uint32_t* __restrict__ mb) {
    int i = blockIdx.x * 256 + threadIdx.x;   // 16777216 threads
    unsigned long long bal = __ballot(mask[i] == 1);
    int lane = threadIdx.x & 63;
    if (lane < 2) {
        int b = i >> 22, q = (i >> 11) & 2047, c = i & 2047;
        int kt = c >> 6;
        mb[((uint64_t)(b * 32 + kt) * 2048 + q) * 2 + lane] =
            (lane == 0) ? (uint32_t)bal : (uint32_t)(bal >> 32);
    }
}

// ---------------------------------------------------------------- GEMM core (dist-2 ring, 32x32x16)
// v13: MFMA 16x16x32 -> 32x32x16 (measured ubench 2382 vs 2075 TF; 8 instead of
// 16 MFMA per K-step). Staging/ring/vmcnt identical to the validated round-5
// structure. A/B frag: row|col = lane&31, k = (lane>>5)*8 + e (direct analog of
// the 16x16x32 mapping used before). C/D: col=lane&31,
// row = (reg&3) + 8*(reg>>2) + 4*(lane>>5)  [HW-verified m74/m101].
template <int KD>
__device__ __forceinline__ void gemm_bt_core(
    const ushort* __restrict__ A, const ushort* __restrict__ Bm,
    int m0, int n0, ushort* L, f32x16 (&acc)[2][2])
{
    constexpr int NST = KD / 32;
    const int tid  = threadIdx.x;
    const int lane = tid & 63;
    const int wave = tid >> 6;
    const int wm = wave >> 1, wn = wave & 1;
    const int fr = lane & 31;            // row/col within 32x32 tile
    const int fk = (lane >> 5) * 8;      // k-offset within 16-k subtile
    const int lrow = lane >> 2;
    const int lk   = (lane & 3) * 8;

#pragma unroll
    for (int i = 0; i < 2; ++i)
#pragma unroll
        for (int j = 0; j < 2; ++j)
#pragma unroll
            for (int e = 0; e < 16; ++e) acc[i][j][e] = 0.f;

    ushort* s0 = L;
    ushort* s1 = L + 8192;
    ushort* s2 = L + 16384;

    const uint64_t arow = (uint64_t)(m0 + lrow) * KD + lk;
    const uint64_t brow = (uint64_t)(n0 + lrow) * KD + lk;

#define GEMM_STAGE(k0, slot)                                                     \
    {                                                                            \
        _Pragma("unroll")                                                        \
        for (int t = 0; t < 2; ++t) {                                            \
            const int r0 = t * 64 + wave * 16;                                   \
            gl2lds16(&A [arow + (uint64_t)r0 * KD + (k0)], &(slot)[r0 * 32]);    \
            gl2lds16(&Bm[brow + (uint64_t)r0 * KD + (k0)], &(slot)[4096 + r0 * 32]); \
        }                                                                        \
    }

    GEMM_STAGE(0, s0);
    GEMM_STAGE(32, s1);
    asm volatile("s_waitcnt vmcnt(4)" ::: "memory");
    __builtin_amdgcn_s_barrier();
    __builtin_amdgcn_sched_barrier(0);

    ushort* cur = s0; ushort* nxt = s1; ushort* tgt = s2;

    for (int kt = 0; kt < NST; ++kt) {
        if (kt < NST - 2) GEMM_STAGE((kt + 2) * 32, tgt);

        bf16x8 af[2][2], bfr[2][2];      // [tile i|j][k-subtile s]
#pragma unroll
        for (int i = 0; i < 2; ++i)
#pragma unroll
            for (int s = 0; s < 2; ++s)
                af[i][s] = *(const bf16x8*)&cur[(wm * 64 + i * 32 + fr) * 32 + s * 16 + fk];
#pragma unroll
        for (int j = 0; j < 2; ++j)
#pragma unroll
            for (int s = 0; s < 2; ++s)
                bfr[j][s] = *(const bf16x8*)&cur[4096 + (wn * 64 + j * 32 + fr) * 32 + s * 16 + fk];
        __builtin_amdgcn_s_setprio(1);
#pragma unroll
        for (int s = 0; s < 2; ++s)
#pragma unroll
            for (int i = 0; i < 2; ++i)
#pragma unroll
                for (int j = 0; j < 2; ++j)
                    acc[i][j] = __builtin_amdgcn_mfma_f32_32x32x16_bf16(
                        af[i][s], bfr[j][s], acc[i][j], 0, 0, 0);
        __builtin_amdgcn_s_setprio(0);

        if (kt < NST - 2) {
            asm volatile("s_waitcnt vmcnt(4)" ::: "memory");
        } else {
            asm volatile("s_waitcnt vmcnt(0)" ::: "memory");
        }
        __builtin_amdgcn_s_barrier();
        __builtin_amdgcn_sched_barrier(0);

        ushort* o = cur; cur = nxt; nxt = tgt; tgt = o;
    }
#undef GEMM_STAGE
}

// ---------------------------------------------------------------- QKV GEMM
// Q pre-scaled by 0.125*log2(e): scores exit QK^T in log2 domain (exp2 softmax).
__global__ __launch_bounds__(256) void qkv_gemm(
    const ushort* __restrict__ xb, const ushort* __restrict__ wb,
    const float* __restrict__ bqkv,
    ushort* __restrict__ qo, ushort* __restrict__ ko, ushort* __restrict__ vto)
{
    __shared__ __align__(16) ushort L[24576];   // 48 KB ring
    f32x16 acc[2][2];
    const int lin = blockIdx.x;                  // 1536 = 8 * 192
    const int swz = (lin & 7) * 192 + (lin >> 3);
    const int m0 = (swz & 63) * 128;
    const int n0 = (swz >> 6) * 128;
    gemm_bt_core<1024>(xb, wb, m0, n0, L, acc);

    const int lane = threadIdx.x & 63, wave = threadIdx.x >> 6;
    const int wm = wave >> 1, wn = wave & 1;
    const int ls = lane >> 5;                    // k-group half
    const float QSC = 0.125f * 1.4426950408889634f;
#pragma unroll
    for (int j = 0; j < 2; ++j) {
        const int n = n0 + wn * 64 + j * 32 + (lane & 31);
        const int h = n / 192, f = n % 192;
        const float bias = bqkv[n];
#pragma unroll
        for (int i2 = 0; i2 < 2; ++i2) {
#pragma unroll
            for (int q = 0; q < 4; ++q) {
                const int mbase = m0 + wm * 64 + i2 * 32 + q * 8 + ls * 4;
                if (f < 128) {
#pragma unroll
                    for (int v = 0; v < 4; ++v) {
                        const int m = mbase + v;
                        const int b = m >> 11, s = m & 2047;
                        const float val = acc[i2][j][q * 4 + v] + bias;
                        if (f < 64) qo[((uint64_t)(b * 16 + h) * 2048 + s) * 64 + f]        = f2b(val * QSC);
                        else        ko[((uint64_t)(b * 16 + h) * 2048 + s) * 64 + (f - 64)] = f2b(val);
                    }
                } else {
                    const int b = mbase >> 11, s = mbase & 2047;
                    ushort4 pk;
                    pk.x = f2b(acc[i2][j][q * 4 + 0] + bias);
                    pk.y = f2b(acc[i2][j][q * 4 + 1] + bias);
                    pk.z = f2b(acc[i2][j][q * 4 + 2] + bias);
                    pk.w = f2b(acc[i2][j][q * 4 + 3] + bias);
                    *(ushort4*)&vto[((uint64_t)(b * 16 + h) * 64 + (f - 128)) * 2048 + s] = pk;
                }
            }
        }
    }
}

// ---------------------------------------------------------------- flash attention v11
// (reverted to the round-7 validated version: 93 us, MfmaUtil 35, WRITE 16MB.
//  Round-8's delayed-PV v12 SPILLED the score double-buffer to scratch --
//  WRITE_SIZE 130MB, attn 164+ us. T15-on-this-structure is refuted: QKT,
//  softmax, PV already share one barrier-to-barrier scheduling region.)
__global__ __launch_bounds__(256, 3) void attn_kernel(
    const ushort* __restrict__ qa, const ushort* __restrict__ ka,
    const ushort* __restrict__ vta, const uint32_t* __restrict__ mbits,
    ushort* __restrict__ ctxo)
{
    __shared__ __align__(16) ushort LDSH[24576];   // 48 KB: 3 x (K 8KB + V 8KB)
    ushort* const Ks0 = LDSH;
    ushort* const Vt0 = LDSH + 4096;
    ushort* const Ks1 = LDSH + 8192;
    ushort* const Vt1 = LDSH + 12288;
    ushort* const Ks2 = LDSH + 16384;
    ushort* const Vt2 = LDSH + 20480;
    ushort* const CTX = LDSH;                      // 16 KB epilogue stage aliases slot 0

    const int bid = blockIdx.x;
    const int bh = (bid & 7) * 8 + (bid >> 7);
    const int qb = (bid >> 3) & 15;
    const int b = bh >> 4;
    const int tid = threadIdx.x, lane = tid & 63, wave = tid >> 6;
    const int col = lane & 15, rg = lane >> 4;

    const uint64_t bhoff = (uint64_t)bh * (S_ * 64);
    const ushort* qp = qa + bhoff + (uint64_t)qb * 128 * 64;
    const ushort* kp = ka + bhoff;
    const ushort* vp = vta + bhoff;                       // [64][2048]
    const uint32_t* mk0 = mbits + ((uint64_t)(b * 32) * 2048 + qb * 128 + wave * 32 + col) * 2;
    const uint32_t* mk1 = mk0 + 32;                       // +16 rows

    const int lr = lane >> 3;
    const int usw = (lane & 7) ^ lr;
    const int r0s = wave * 16 + lr;
    const int r1s = r0s + 8;
    const int sg0 = (r0s & 32) | ((r0s & 12) << 1) | ((r0s & 16) >> 2) | (r0s & 3);
    const int sg1 = (r1s & 32) | ((r1s & 12) << 1) | ((r1s & 16) >> 2) | (r1s & 3);
    const int kb0 = sg0 * 64 + usw * 8;
    const int kb1 = sg1 * 64 + usw * 8;
    const int vb0 = r0s * 2048 + usw * 8;
    const int vb1 = r1s * 2048 + usw * 8;
    const int ldst0 = wave * 1024;
    const int ldst1 = ldst0 + 512;

    bf16x8 aq[2][2];
#pragma unroll
    for (int i = 0; i < 2; ++i)
#pragma unroll
        for (int k2 = 0; k2 < 2; ++k2)
            aq[i][k2] = *(const bf16x8*)&qp[(wave * 32 + i * 16 + col) * 64 + k2 * 32 + rg * 8];

    gl2lds16(&kp[kb0], &Ks0[ldst0]);
    gl2lds16(&kp[kb1], &Ks0[ldst1]);
    gl2lds16(&vp[vb0], &Vt0[ldst0]);
    gl2lds16(&vp[vb1], &Vt0[ldst1]);
    uint2 m_cur0 = *(const uint2*)mk0;
    uint2 m_cur1 = *(const uint2*)mk1;
    gl2lds16(&kp[4096 + kb0], &Ks1[ldst0]);
    gl2lds16(&kp[4096 + kb1], &Ks1[ldst1]);
    gl2lds16(&vp[vb0 + 64], &Vt1[ldst0]);
    gl2lds16(&vp[vb1 + 64], &Vt1[ldst1]);
    uint2 m_nxt0 = *(const uint2*)(mk0 + 4096);
    uint2 m_nxt1 = *(const uint2*)(mk1 + 4096);
    uint2 m_new0 = m_nxt0, m_new1 = m_nxt1;
    asm volatile("s_waitcnt vmcnt(0)" ::: "memory");
    __builtin_amdgcn_s_barrier();
    __builtin_amdgcn_sched_barrier(0);

    const f32x4 fz = {0.f, 0.f, 0.f, 0.f};
    f32x4 acc[4][2];
#pragma unroll
    for (int dt = 0; dt < 4; ++dt)
#pragma unroll
        for (int i = 0; i < 2; ++i) acc[dt][i] = fz;
    f32x4 acc5[2] = {fz, fz};

    bf16x8 vone;
#pragma unroll
    for (int e = 0; e < 8; ++e) vone[e] = (short)0x3F80;

    int bpos[2][4];
#pragma unroll
    for (int p = 0; p < 2; ++p)
#pragma unroll
        for (int v = 0; v < 4; ++v) bpos[p][v] = rg * 8 + p * 4 + v;

    const int u0 = (rg ^ (col & 7)) << 3;

    const ushort* cK = Ks0; const ushort* cV = Vt0;
    const ushort* nK = Ks1; const ushort* nV = Vt1;
    ushort* tK = Ks2; ushort* tV = Vt2;

    for (int kt = 0; kt < 32; ++kt) {
        if (kt < 30) {
            const int k2 = (kt + 2) * 4096;
            gl2lds16(&kp[k2 + kb0], &tK[ldst0]);
            gl2lds16(&kp[k2 + kb1], &tK[ldst1]);
            gl2lds16(&vp[vb0 + (kt + 2) * 64], &tV[ldst0]);
            gl2lds16(&vp[vb1 + (kt + 2) * 64], &tV[ldst1]);
            m_new0 = *(const uint2*)(mk0 + (uint64_t)(kt + 2) * 4096);
            m_new1 = *(const uint2*)(mk1 + (uint64_t)(kt + 2) * 4096);
        }

        // scores S^T (log2 domain)
        f32x4 sc[2][4];
        __builtin_amdgcn_s_setprio(1);
#pragma unroll
        for (int j = 0; j < 4; ++j) {
            bf16x8 bk0 = *(const bf16x8*)&cK[(j * 16 + col) * 64 + u0];
            bf16x8 bk1 = *(const bf16x8*)&cK[(j * 16 + col) * 64 + (u0 ^ 32)];
#pragma unroll
            for (int i = 0; i < 2; ++i) {
                f32x4 z = __builtin_amdgcn_mfma_f32_16x16x32_bf16(bk0, aq[i][0], fz, 0, 0, 0);
                sc[i][j] = __builtin_amdgcn_mfma_f32_16x16x32_bf16(bk1, aq[i][1], z, 0, 0, 0);
            }
        }
        __builtin_amdgcn_s_setprio(0);

        // mask + exp2 (thinned) -> P fragments
        bf16x8 bp[2][2];
#pragma unroll
        for (int i = 0; i < 2; ++i) {
            const uint2 mw = i ? m_cur1 : m_cur0;
            const uint32_t wnx = ~mw.x, wny = ~mw.y;
            union { uint32_t w[4]; bf16x8 v; } p0, p1;
#pragma unroll
            for (int j = 0; j < 4; ++j) {
                const uint32_t wn = (j & 2) ? wny : wnx;
                const int p = j & 1;
                float pe[4];
#pragma unroll
                for (int v = 0; v < 4; ++v) {
                    union { float f; uint32_t u; } cu;
                    cu.f = sc[i][j][v];
                    cu.u &= keepmask(wn, bpos[p][v]);
                    pe[v] = EXP2(cu.f);
                }
                const uint32_t lo = pkbf_t(pe[0], pe[1]);
                const uint32_t hi = pkbf_t(pe[2], pe[3]);
                if (j < 2) { p0.w[p * 2] = lo; p0.w[p * 2 + 1] = hi; }
                else       { p1.w[p * 2] = lo; p1.w[p * 2 + 1] = hi; }
            }
            bp[i][0] = p0.v;
            bp[i][1] = p1.v;
        }

        // PV + denominator
        __builtin_amdgcn_s_setprio(1);
#pragma unroll
        for (int i = 0; i < 2; ++i) {
            acc5[i] = __builtin_amdgcn_mfma_f32_16x16x32_bf16(vone, bp[i][0], acc5[i], 0, 0, 0);
            acc5[i] = __builtin_amdgcn_mfma_f32_16x16x32_bf16(vone, bp[i][1], acc5[i], 0, 0, 0);
        }
#pragma unroll
        for (int dt = 0; dt < 4; ++dt) {
            bf16x8 av0 = *(const bf16x8*)&cV[(dt * 16 + col) * 64 + u0];
            bf16x8 av1 = *(const bf16x8*)&cV[(dt * 16 + col) * 64 + (u0 ^ 32)];
#pragma unroll
            for (int i = 0; i < 2; ++i) {
                acc[dt][i] = __builtin_amdgcn_mfma_f32_16x16x32_bf16(av0, bp[i][0], acc[dt][i], 0, 0, 0);
                acc[dt][i] = __builtin_amdgcn_mfma_f32_16x16x32_bf16(av1, bp[i][1], acc[dt][i], 0, 0, 0);
            }
        }
        __builtin_amdgcn_s_setprio(0);

        if (kt < 30) {
            asm volatile("s_waitcnt vmcnt(6)" ::: "memory");
        } else {
            asm volatile("s_waitcnt vmcnt(0)" ::: "memory");
        }
        __builtin_amdgcn_s_barrier();
        __builtin_amdgcn_sched_barrier(0);

        const ushort* oK = cK; const ushort* oV = cV;
        cK = nK; cV = nV; nK = tK; nV = tV; tK = (ushort*)oK; tV = (ushort*)oV;
        m_cur0 = m_nxt0; m_cur1 = m_nxt1; m_nxt0 = m_new0; m_nxt1 = m_new1;
    }

    float linv[2];
#pragma unroll
    for (int i = 0; i < 2; ++i) linv[i] = 1.0f / acc5[i][0];

#pragma unroll
    for (int dt = 0; dt < 4; ++dt)
#pragma unroll
        for (int i = 0; i < 2; ++i) {
            const int q = wave * 32 + i * 16 + col;
            const int d = dt * 16 + rg * 4;
            const int gg = (d >> 3) ^ (q & 7);
            ushort4 pk;
            pk.x = f2b(acc[dt][i][0] * linv[i]);
            pk.y = f2b(acc[dt][i][1] * linv[i]);
            pk.z = f2b(acc[dt][i][2] * linv[i]);
            pk.w = f2b(acc[dt][i][3] * linv[i]);
            *(ushort4*)&CTX[q * 64 + gg * 8 + (d & 7)] = pk;
        }
    __syncthreads();
    const int h = bh & 15;
    const uint64_t obase = (uint64_t)(b * S_ + qb * 128) * E_ + (uint64_t)h * 64;
#pragma unroll
    for (int t4 = 0; t4 < 4; ++t4) {
        const int id = tid + t4 * 256;
        const int r = id >> 3, c8 = id & 7;
        *(bf16x8*)&ctxo[obase + (uint64_t)r * E_ + c8 * 8] =
            *(const bf16x8*)&CTX[r * 64 + ((c8 ^ (r & 7)) << 3)];
    }
}

// ---------------------------------------------------------------- output GEMM
__global__ __launch_bounds__(256) void out_gemm(
    const ushort* __restrict__ ctxb, const ushort* __restrict__ wob,
    const float* __restrict__ bo, float* __restrict__ out)
{
    __shared__ __align__(16) ushort L[24576];   // 48 KB ring
    f32x16 acc[2][2];
    const int lin = blockIdx.x;
    const int swz = (lin & 7) * 64 + (lin >> 3);
    const int m0 = (swz & 63) * 128;
    const int n0 = (swz >> 6) * 128;
    gemm_bt_core<1024>(ctxb, wob, m0, n0, L, acc);

    const int lane = threadIdx.x & 63, wave = threadIdx.x >> 6;
    const int wm = wave >> 1, wn = wave & 1;
    const int ls = lane >> 5;
#pragma unroll
    for (int j = 0; j < 2; ++j) {
        const int n = n0 + wn * 64 + j * 32 + (lane & 31);
        const float bias = bo[n];
#pragma unroll
        for (int i2 = 0; i2 < 2; ++i2) {
#pragma unroll
            for (int q = 0; q < 4; ++q) {
                const int mbase = m0 + wm * 64 + i2 * 32 + q * 8 + ls * 4;
#pragma unroll
                for (int v = 0; v < 4; ++v)
                    out[(uint64_t)(mbase + v) * 1024 + n] = acc[i2][j][q * 4 + v] + bias;
            }
        }
    }
}

// ---------------------------------------------------------------- launch
extern "C" void kernel_launch(void* const* d_in, const int* in_sizes, int n_in,
                              void* d_out, int out_size, void* d_ws, size_t ws_size,
                              hipStream_t stream)
{
    const float* x    = (const float*)d_in[0];
    const int*   mask = (const int*)d_in[1];
    const float* Wqkv = (const float*)d_in[2];
    const float* bqkv = (const float*)d_in[3];
    const float* Wo   = (const float*)d_in[4];
    const float* bo   = (const float*)d_in[5];
    float* out = (float*)d_out;

    char* p = (char*)d_ws;
    ushort* xb  = (ushort*)p; p += (size_t)8388608 * 2;   // x bf16 [8192][1024]
    ushort* wqb = (ushort*)p; p += (size_t)3145728 * 2;   // Wqkv bf16 [3072][1024]
    ushort* wob = (ushort*)p; p += (size_t)1048576 * 2;   // Wo bf16 [1024][1024]
    ushort* qo  = (ushort*)p; p += (size_t)8388608 * 2;   // Q bf16 (log2-domain prescale)
    ushort* ko  = (ushort*)p; p += (size_t)8388608 * 2;   // K bf16 [bh][s][64]
    ushort* vto = (ushort*)p; p += (size_t)8388608 * 2;   // V^T bf16 [bh][64][s]
    ushort* ctx = (ushort*)p; p += (size_t)8388608 * 2;   // ctx bf16 [8192][1024]
    uint32_t* mb = (uint32_t*)p;                          // packed mask bits (kt-major), 2 MB

    cvt_all<<<12288, 256, 0, stream>>>(x, Wqkv, Wo, xb, wqb, wob);
    pack_mask<<<65536, 256, 0, stream>>>(mask, mb);
    qkv_gemm<<<1536, 256, 0, stream>>>(xb, wqb, bqkv, qo, ko, vto);
    attn_kernel<<<1024, 256, 0, stream>>>(qo, ko, vto, mb, ctx);
    out_gemm<<<512, 256, 0, stream>>>(ctx, wob, bo, out);
}

// Round 10
// 353.529 us; speedup vs baseline: 1.1919x; 1.0208x over previous
//
#include <hip/hip_runtime.h>
#include <stdint.h>

// Problem constants
#define B_ 4
#define S_ 2048
#define E_ 1024
#define H_ 16
#define HD_ 64

typedef __attribute__((ext_vector_type(8))) short bf16x8;    // 8 bf16 = 4 VGPRs (MFMA A/B frag)
typedef __attribute__((ext_vector_type(4))) float f32x4;     // 16x16 MFMA C/D frag
typedef __attribute__((ext_vector_type(16))) float f32x16;   // 32x32 MFMA C/D frag

__device__ __forceinline__ ushort f2b(float f) {
    union { float f; uint32_t u; } c; c.f = f;
    return (ushort)((c.u + 0x8000u) >> 16);   // round-to-nearest (ties up)
}

// truncating pack: two f32 -> {bf16_trunc(a) lo, bf16_trunc(b) hi} in ONE v_perm.
// Used ONLY for P in attn: the same truncated P feeds numerator (PV) and
// denominator (ones-MFMA), so the <=2^-8 truncation bias cancels in the ratio.
__device__ __forceinline__ uint32_t pkbf_t(float a, float b) {
    union { float f; uint32_t u; } ca, cb; ca.f = a; cb.f = b;
#if __has_builtin(__builtin_amdgcn_perm)
    return __builtin_amdgcn_perm(cb.u, ca.u, 0x07060302u);
#else
    return (ca.u >> 16) | (cb.u & 0xFFFF0000u);
#endif
}

// all-ones iff bit `pos` of wn is set (1 op: v_bfe_i32)
__device__ __forceinline__ uint32_t keepmask(uint32_t wn, int pos) {
#if __has_builtin(__builtin_amdgcn_sbfe)
    return (uint32_t)__builtin_amdgcn_sbfe((int)wn, pos, 1);
#else
    return (uint32_t)(((int32_t)(wn << (31 - pos))) >> 31);
#endif
}

#if __has_builtin(__builtin_amdgcn_exp2f)
#define EXP2(x) __builtin_amdgcn_exp2f(x)
#else
#define EXP2(x) exp2f(x)
#endif

// async global->LDS, 16B per lane; LDS dest = wave-uniform base + lane*16,
// global src = PER-LANE address (gather) -> source-side permutations are free.
__device__ __forceinline__ void gl2lds16(const ushort* g, const ushort* l) {
    __builtin_amdgcn_global_load_lds(
        (const __attribute__((address_space(1))) unsigned int*)g,
        (__attribute__((address_space(3))) unsigned int*)l,
        16, 0, 0);
}

// ---------------------------------------------------------------- fused converts
__global__ __launch_bounds__(256) void cvt_all(
    const float* __restrict__ x, const float* __restrict__ wq, const float* __restrict__ wo,
    ushort* __restrict__ xb, ushort* __restrict__ wqb, ushort* __restrict__ wob) {
    int i = blockIdx.x * 256 + threadIdx.x;
    const float* src; ushort* dst; int off;
    if (i < 2097152)      { src = x;  dst = xb;  off = i; }
    else if (i < 2883584) { src = wq; dst = wqb; off = i - 2097152; }
    else                  { src = wo; dst = wob; off = i - 2883584; }
    float4 f = ((const float4*)src)[off];
    ushort4 o;
    o.x = f2b(f.x); o.y = f2b(f.y); o.z = f2b(f.z); o.w = f2b(f.w);
    ((ushort4*)dst)[off] = o;
}

// mask [B,S,S] int32 (0/1) -> bit-packed, kt-major:
// mb[((b*32 + kt)*2048 + q)*2 + w] bit c = mask[b][q][kt*64 + w*32 + c]
__global__ __launch_bounds__(256) void pack_mask(const int* __restrict__ mask,
                                                 uint32_t* __restrict__ mb) {
    int i = blockIdx.x * 256 + threadIdx.x;   // 16777216 threads
    unsigned long long bal = __ballot(mask[i] == 1);
    int lane = threadIdx.x & 63;
    if (lane < 2) {
        int b = i >> 22, q = (i >> 11) & 2047, c = i & 2047;
        int kt = c >> 6;
        mb[((uint64_t)(b * 32 + kt) * 2048 + q) * 2 + lane] =
            (lane == 0) ? (uint32_t)bal : (uint32_t)(bal >> 32);
    }
}

// ---------------------------------------------------------------- GEMM core (dist-2 ring, 32x32x16, T2-swizzled LDS)
// Round-9 PMC: SQ_LDS_BANK_CONFLICT 1.89e7 (~31 us/CU) with the linear tile --
// the 32x32 fragment read puts 16 lanes on one bank-quad. Fix (rule #21,
// both-sides): physical 16B-unit c' = c ^ ((row>>1)&3).
//   * staging (gl2lds writes linearly at lane*16): inverse-permute the GLOBAL
//     source k-chunk: lk = ((lane&3) ^ ((lane>>3)&3)) * 8   [row bits 1-2 of
//     the 16-row group = lane>>3]
//   * fragment read: unit (s*2 + lane>>5) ^ ((lane>>1)&3)   [row bits 1-2 of
//     fr = lane>>1] -> uniform 8 accesses/bank (hardware floor).
template <int KD>
__device__ __forceinline__ void gemm_bt_core(
    const ushort* __restrict__ A, const ushort* __restrict__ Bm,
    int m0, int n0, ushort* L, f32x16 (&acc)[2][2])
{
    constexpr int NST = KD / 32;
    const int tid  = threadIdx.x;
    const int lane = tid & 63;
    const int wave = tid >> 6;
    const int wm = wave >> 1, wn = wave & 1;
    const int fr = lane & 31;            // row/col within 32x32 tile
    const int fq = lane >> 5;            // k-half selector
    const int fsw = (lane >> 1) & 3;     // row bits 1-2 (read-side swizzle)
    const int lrow = lane >> 2;
    const int lk   = (((lane & 3) ^ ((lane >> 3) & 3)) * 8);  // swizzled source k-chunk

#pragma unroll
    for (int i = 0; i < 2; ++i)
#pragma unroll
        for (int j = 0; j < 2; ++j)
#pragma unroll
            for (int e = 0; e < 16; ++e) acc[i][j][e] = 0.f;

    ushort* s0 = L;
    ushort* s1 = L + 8192;
    ushort* s2 = L + 16384;

    const uint64_t arow = (uint64_t)(m0 + lrow) * KD + lk;
    const uint64_t brow = (uint64_t)(n0 + lrow) * KD + lk;

#define GEMM_STAGE(k0, slot)                                                     \
    {                                                                            \
        _Pragma("unroll")                                                        \
        for (int t = 0; t < 2; ++t) {                                            \
            const int r0 = t * 64 + wave * 16;                                   \
            gl2lds16(&A [arow + (uint64_t)r0 * KD + (k0)], &(slot)[r0 * 32]);    \
            gl2lds16(&Bm[brow + (uint64_t)r0 * KD + (k0)], &(slot)[4096 + r0 * 32]); \
        }                                                                        \
    }

    GEMM_STAGE(0, s0);
    GEMM_STAGE(32, s1);
    asm volatile("s_waitcnt vmcnt(4)" ::: "memory");
    __builtin_amdgcn_s_barrier();
    __builtin_amdgcn_sched_barrier(0);

    ushort* cur = s0; ushort* nxt = s1; ushort* tgt = s2;

    for (int kt = 0; kt < NST; ++kt) {
        if (kt < NST - 2) GEMM_STAGE((kt + 2) * 32, tgt);

        bf16x8 af[2][2], bfr[2][2];      // [tile i|j][k-subtile s]
#pragma unroll
        for (int i = 0; i < 2; ++i)
#pragma unroll
            for (int s = 0; s < 2; ++s)
                af[i][s] = *(const bf16x8*)&cur[(wm * 64 + i * 32 + fr) * 32 +
                                                 (((s * 2 + fq) ^ fsw) * 8)];
#pragma unroll
        for (int j = 0; j < 2; ++j)
#pragma unroll
            for (int s = 0; s < 2; ++s)
                bfr[j][s] = *(const bf16x8*)&cur[4096 + (wn * 64 + j * 32 + fr) * 32 +
                                                  (((s * 2 + fq) ^ fsw) * 8)];
        __builtin_amdgcn_s_setprio(1);
#pragma unroll
        for (int s = 0; s < 2; ++s)
#pragma unroll
            for (int i = 0; i < 2; ++i)
#pragma unroll
                for (int j = 0; j < 2; ++j)
                    acc[i][j] = __builtin_amdgcn_mfma_f32_32x32x16_bf16(
                        af[i][s], bfr[j][s], acc[i][j], 0, 0, 0);
        __builtin_amdgcn_s_setprio(0);

        if (kt < NST - 2) {
            asm volatile("s_waitcnt vmcnt(4)" ::: "memory");
        } else {
            asm volatile("s_waitcnt vmcnt(0)" ::: "memory");
        }
        __builtin_amdgcn_s_barrier();
        __builtin_amdgcn_sched_barrier(0);

        ushort* o = cur; cur = nxt; nxt = tgt; tgt = o;
    }
#undef GEMM_STAGE
}

// ---------------------------------------------------------------- QKV GEMM
// Q pre-scaled by 0.125*log2(e): scores exit QK^T in log2 domain (exp2 softmax).
__global__ __launch_bounds__(256) void qkv_gemm(
    const ushort* __restrict__ xb, const ushort* __restrict__ wb,
    const float* __restrict__ bqkv,
    ushort* __restrict__ qo, ushort* __restrict__ ko, ushort* __restrict__ vto)
{
    __shared__ __align__(16) ushort L[24576];   // 48 KB ring
    f32x16 acc[2][2];
    const int lin = blockIdx.x;                  // 1536 = 8 * 192
    const int swz = (lin & 7) * 192 + (lin >> 3);
    const int m0 = (swz & 63) * 128;
    const int n0 = (swz >> 6) * 128;
    gemm_bt_core<1024>(xb, wb, m0, n0, L, acc);

    const int lane = threadIdx.x & 63, wave = threadIdx.x >> 6;
    const int wm = wave >> 1, wn = wave & 1;
    const int ls = lane >> 5;                    // k-group half
    const float QSC = 0.125f * 1.4426950408889634f;
#pragma unroll
    for (int j = 0; j < 2; ++j) {
        const int n = n0 + wn * 64 + j * 32 + (lane & 31);
        const int h = n / 192, f = n % 192;
        const float bias = bqkv[n];
#pragma unroll
        for (int i2 = 0; i2 < 2; ++i2) {
#pragma unroll
            for (int q = 0; q < 4; ++q) {
                const int mbase = m0 + wm * 64 + i2 * 32 + q * 8 + ls * 4;
                if (f < 128) {
#pragma unroll
                    for (int v = 0; v < 4; ++v) {
                        const int m = mbase + v;
                        const int b = m >> 11, s = m & 2047;
                        const float val = acc[i2][j][q * 4 + v] + bias;
                        if (f < 64) qo[((uint64_t)(b * 16 + h) * 2048 + s) * 64 + f]        = f2b(val * QSC);
                        else        ko[((uint64_t)(b * 16 + h) * 2048 + s) * 64 + (f - 64)] = f2b(val);
                    }
                } else {
                    const int b = mbase >> 11, s = mbase & 2047;
                    ushort4 pk;
                    pk.x = f2b(acc[i2][j][q * 4 + 0] + bias);
                    pk.y = f2b(acc[i2][j][q * 4 + 1] + bias);
                    pk.z = f2b(acc[i2][j][q * 4 + 2] + bias);
                    pk.w = f2b(acc[i2][j][q * 4 + 3] + bias);
                    *(ushort4*)&vto[((uint64_t)(b * 16 + h) * 64 + (f - 128)) * 2048 + s] = pk;
                }
            }
        }
    }
}

// ---------------------------------------------------------------- flash attention v11
// (validated: 93 us, MfmaUtil 35, WRITE 16MB; unchanged)
__global__ __launch_bounds__(256, 3) void attn_kernel(
    const ushort* __restrict__ qa, const ushort* __restrict__ ka,
    const ushort* __restrict__ vta, const uint32_t* __restrict__ mbits,
    ushort* __restrict__ ctxo)
{
    __shared__ __align__(16) ushort LDSH[24576];   // 48 KB: 3 x (K 8KB + V 8KB)
    ushort* const Ks0 = LDSH;
    ushort* const Vt0 = LDSH + 4096;
    ushort* const Ks1 = LDSH + 8192;
    ushort* const Vt1 = LDSH + 12288;
    ushort* const Ks2 = LDSH + 16384;
    ushort* const Vt2 = LDSH + 20480;
    ushort* const CTX = LDSH;                      // 16 KB epilogue stage aliases slot 0

    const int bid = blockIdx.x;
    const int bh = (bid & 7) * 8 + (bid >> 7);
    const int qb = (bid >> 3) & 15;
    const int b = bh >> 4;
    const int tid = threadIdx.x, lane = tid & 63, wave = tid >> 6;
    const int col = lane & 15, rg = lane >> 4;

    const uint64_t bhoff = (uint64_t)bh * (S_ * 64);
    const ushort* qp = qa + bhoff + (uint64_t)qb * 128 * 64;
    const ushort* kp = ka + bhoff;
    const ushort* vp = vta + bhoff;                       // [64][2048]
    const uint32_t* mk0 = mbits + ((uint64_t)(b * 32) * 2048 + qb * 128 + wave * 32 + col) * 2;
    const uint32_t* mk1 = mk0 + 32;                       // +16 rows

    const int lr = lane >> 3;
    const int usw = (lane & 7) ^ lr;
    const int r0s = wave * 16 + lr;
    const int r1s = r0s + 8;
    const int sg0 = (r0s & 32) | ((r0s & 12) << 1) | ((r0s & 16) >> 2) | (r0s & 3);
    const int sg1 = (r1s & 32) | ((r1s & 12) << 1) | ((r1s & 16) >> 2) | (r1s & 3);
    const int kb0 = sg0 * 64 + usw * 8;
    const int kb1 = sg1 * 64 + usw * 8;
    const int vb0 = r0s * 2048 + usw * 8;
    const int vb1 = r1s * 2048 + usw * 8;
    const int ldst0 = wave * 1024;
    const int ldst1 = ldst0 + 512;

    bf16x8 aq[2][2];
#pragma unroll
    for (int i = 0; i < 2; ++i)
#pragma unroll
        for (int k2 = 0; k2 < 2; ++k2)
            aq[i][k2] = *(const bf16x8*)&qp[(wave * 32 + i * 16 + col) * 64 + k2 * 32 + rg * 8];

    gl2lds16(&kp[kb0], &Ks0[ldst0]);
    gl2lds16(&kp[kb1], &Ks0[ldst1]);
    gl2lds16(&vp[vb0], &Vt0[ldst0]);
    gl2lds16(&vp[vb1], &Vt0[ldst1]);
    uint2 m_cur0 = *(const uint2*)mk0;
    uint2 m_cur1 = *(const uint2*)mk1;
    gl2lds16(&kp[4096 + kb0], &Ks1[ldst0]);
    gl2lds16(&kp[4096 + kb1], &Ks1[ldst1]);
    gl2lds16(&vp[vb0 + 64], &Vt1[ldst0]);
    gl2lds16(&vp[vb1 + 64], &Vt1[ldst1]);
    uint2 m_nxt0 = *(const uint2*)(mk0 + 4096);
    uint2 m_nxt1 = *(const uint2*)(mk1 + 4096);
    uint2 m_new0 = m_nxt0, m_new1 = m_nxt1;
    asm volatile("s_waitcnt vmcnt(0)" ::: "memory");
    __builtin_amdgcn_s_barrier();
    __builtin_amdgcn_sched_barrier(0);

    const f32x4 fz = {0.f, 0.f, 0.f, 0.f};
    f32x4 acc[4][2];
#pragma unroll
    for (int dt = 0; dt < 4; ++dt)
#pragma unroll
        for (int i = 0; i < 2; ++i) acc[dt][i] = fz;
    f32x4 acc5[2] = {fz, fz};

    bf16x8 vone;
#pragma unroll
    for (int e = 0; e < 8; ++e) vone[e] = (short)0x3F80;

    int bpos[2][4];
#pragma unroll
    for (int p = 0; p < 2; ++p)
#pragma unroll
        for (int v = 0; v < 4; ++v) bpos[p][v] = rg * 8 + p * 4 + v;

    const int u0 = (rg ^ (col & 7)) << 3;

    const ushort* cK = Ks0; const ushort* cV = Vt0;
    const ushort* nK = Ks1; const ushort* nV = Vt1;
    ushort* tK = Ks2; ushort* tV = Vt2;

    for (int kt = 0; kt < 32; ++kt) {
        if (kt < 30) {
            const int k2 = (kt + 2) * 4096;
            gl2lds16(&kp[k2 + kb0], &tK[ldst0]);
            gl2lds16(&kp[k2 + kb1], &tK[ldst1]);
            gl2lds16(&vp[vb0 + (kt + 2) * 64], &tV[ldst0]);
            gl2lds16(&vp[vb1 + (kt + 2) * 64], &tV[ldst1]);
            m_new0 = *(const uint2*)(mk0 + (uint64_t)(kt + 2) * 4096);
            m_new1 = *(const uint2*)(mk1 + (uint64_t)(kt + 2) * 4096);
        }

        // scores S^T (log2 domain)
        f32x4 sc[2][4];
        __builtin_amdgcn_s_setprio(1);
#pragma unroll
        for (int j = 0; j < 4; ++j) {
            bf16x8 bk0 = *(const bf16x8*)&cK[(j * 16 + col) * 64 + u0];
            bf16x8 bk1 = *(const bf16x8*)&cK[(j * 16 + col) * 64 + (u0 ^ 32)];
#pragma unroll
            for (int i = 0; i < 2; ++i) {
                f32x4 z = __builtin_amdgcn_mfma_f32_16x16x32_bf16(bk0, aq[i][0], fz, 0, 0, 0);
                sc[i][j] = __builtin_amdgcn_mfma_f32_16x16x32_bf16(bk1, aq[i][1], z, 0, 0, 0);
            }
        }
        __builtin_amdgcn_s_setprio(0);

        // mask + exp2 (thinned) -> P fragments
        bf16x8 bp[2][2];
#pragma unroll
        for (int i = 0; i < 2; ++i) {
            const uint2 mw = i ? m_cur1 : m_cur0;
            const uint32_t wnx = ~mw.x, wny = ~mw.y;
            union { uint32_t w[4]; bf16x8 v; } p0, p1;
#pragma unroll
            for (int j = 0; j < 4; ++j) {
                const uint32_t wn = (j & 2) ? wny : wnx;
                const int p = j & 1;
                float pe[4];
#pragma unroll
                for (int v = 0; v < 4; ++v) {
                    union { float f; uint32_t u; } cu;
                    cu.f = sc[i][j][v];
                    cu.u &= keepmask(wn, bpos[p][v]);
                    pe[v] = EXP2(cu.f);
                }
                const uint32_t lo = pkbf_t(pe[0], pe[1]);
                const uint32_t hi = pkbf_t(pe[2], pe[3]);
                if (j < 2) { p0.w[p * 2] = lo; p0.w[p * 2 + 1] = hi; }
                else       { p1.w[p * 2] = lo; p1.w[p * 2 + 1] = hi; }
            }
            bp[i][0] = p0.v;
            bp[i][1] = p1.v;
        }

        // PV + denominator
        __builtin_amdgcn_s_setprio(1);
#pragma unroll
        for (int i = 0; i < 2; ++i) {
            acc5[i] = __builtin_amdgcn_mfma_f32_16x16x32_bf16(vone, bp[i][0], acc5[i], 0, 0, 0);
            acc5[i] = __builtin_amdgcn_mfma_f32_16x16x32_bf16(vone, bp[i][1], acc5[i], 0, 0, 0);
        }
#pragma unroll
        for (int dt = 0; dt < 4; ++dt) {
            bf16x8 av0 = *(const bf16x8*)&cV[(dt * 16 + col) * 64 + u0];
            bf16x8 av1 = *(const bf16x8*)&cV[(dt * 16 + col) * 64 + (u0 ^ 32)];
#pragma unroll
            for (int i = 0; i < 2; ++i) {
                acc[dt][i] = __builtin_amdgcn_mfma_f32_16x16x32_bf16(av0, bp[i][0], acc[dt][i], 0, 0, 0);
                acc[dt][i] = __builtin_amdgcn_mfma_f32_16x16x32_bf16(av1, bp[i][1], acc[dt][i], 0, 0, 0);
            }
        }
        __builtin_amdgcn_s_setprio(0);

        if (kt < 30) {
            asm volatile("s_waitcnt vmcnt(6)" ::: "memory");
        } else {
            asm volatile("s_waitcnt vmcnt(0)" ::: "memory");
        }
        __builtin_amdgcn_s_barrier();
        __builtin_amdgcn_sched_barrier(0);

        const ushort* oK = cK; const ushort* oV = cV;
        cK = nK; cV = nV; nK = tK; nV = tV; tK = (ushort*)oK; tV = (ushort*)oV;
        m_cur0 = m_nxt0; m_cur1 = m_nxt1; m_nxt0 = m_new0; m_nxt1 = m_new1;
    }

    float linv[2];
#pragma unroll
    for (int i = 0; i < 2; ++i) linv[i] = 1.0f / acc5[i][0];

#pragma unroll
    for (int dt = 0; dt < 4; ++dt)
#pragma unroll
        for (int i = 0; i < 2; ++i) {
            const int q = wave * 32 + i * 16 + col;
            const int d = dt * 16 + rg * 4;
            const int gg = (d >> 3) ^ (q & 7);
            ushort4 pk;
            pk.x = f2b(acc[dt][i][0] * linv[i]);
            pk.y = f2b(acc[dt][i][1] * linv[i]);
            pk.z = f2b(acc[dt][i][2] * linv[i]);
            pk.w = f2b(acc[dt][i][3] * linv[i]);
            *(ushort4*)&CTX[q * 64 + gg * 8 + (d & 7)] = pk;
        }
    __syncthreads();
    const int h = bh & 15;
    const uint64_t obase = (uint64_t)(b * S_ + qb * 128) * E_ + (uint64_t)h * 64;
#pragma unroll
    for (int t4 = 0; t4 < 4; ++t4) {
        const int id = tid + t4 * 256;
        const int r = id >> 3, c8 = id & 7;
        *(bf16x8*)&ctxo[obase + (uint64_t)r * E_ + c8 * 8] =
            *(const bf16x8*)&CTX[r * 64 + ((c8 ^ (r & 7)) << 3)];
    }
}

// ---------------------------------------------------------------- output GEMM
__global__ __launch_bounds__(256) void out_gemm(
    const ushort* __restrict__ ctxb, const ushort* __restrict__ wob,
    const float* __restrict__ bo, float* __restrict__ out)
{
    __shared__ __align__(16) ushort L[24576];   // 48 KB ring
    f32x16 acc[2][2];
    const int lin = blockIdx.x;
    const int swz = (lin & 7) * 64 + (lin >> 3);
    const int m0 = (swz & 63) * 128;
    const int n0 = (swz >> 6) * 128;
    gemm_bt_core<1024>(ctxb, wob, m0, n0, L, acc);

    const int lane = threadIdx.x & 63, wave = threadIdx.x >> 6;
    const int wm = wave >> 1, wn = wave & 1;
    const int ls = lane >> 5;
#pragma unroll
    for (int j = 0; j < 2; ++j) {
        const int n = n0 + wn * 64 + j * 32 + (lane & 31);
        const float bias = bo[n];
#pragma unroll
        for (int i2 = 0; i2 < 2; ++i2) {
#pragma unroll
            for (int q = 0; q < 4; ++q) {
                const int mbase = m0 + wm * 64 + i2 * 32 + q * 8 + ls * 4;
#pragma unroll
                for (int v = 0; v < 4; ++v)
                    out[(uint64_t)(mbase + v) * 1024 + n] = acc[i2][j][q * 4 + v] + bias;
            }
        }
    }
}

// ---------------------------------------------------------------- launch
extern "C" void kernel_launch(void* const* d_in, const int* in_sizes, int n_in,
                              void* d_out, int out_size, void* d_ws, size_t ws_size,
                              hipStream_t stream)
{
    const float* x    = (const float*)d_in[0];
    const int*   mask = (const int*)d_in[1];
    const float* Wqkv = (const float*)d_in[2];
    const float* bqkv = (const float*)d_in[3];
    const float* Wo   = (const float*)d_in[4];
    const float* bo   = (const float*)d_in[5];
    float* out = (float*)d_out;

    char* p = (char*)d_ws;
    ushort* xb  = (ushort*)p; p += (size_t)8388608 * 2;   // x bf16 [8192][1024]
    ushort* wqb = (ushort*)p; p += (size_t)3145728 * 2;   // Wqkv bf16 [3072][1024]
    ushort* wob = (ushort*)p; p += (size_t)1048576 * 2;   // Wo bf16 [1024][1024]
    ushort* qo  = (ushort*)p; p += (size_t)8388608 * 2;   // Q bf16 (log2-domain prescale)
    ushort* ko  = (ushort*)p; p += (size_t)8388608 * 2;   // K bf16 [bh][s][64]
    ushort* vto = (ushort*)p; p += (size_t)8388608 * 2;   // V^T bf16 [bh][64][s]
    ushort* ctx = (ushort*)p; p += (size_t)8388608 * 2;   // ctx bf16 [8192][1024]
    uint32_t* mb = (uint32_t*)p;                          // packed mask bits (kt-major), 2 MB

    cvt_all<<<12288, 256, 0, stream>>>(x, Wqkv, Wo, xb, wqb, wob);
    pack_mask<<<65536, 256, 0, stream>>>(mask, mb);
    qkv_gemm<<<1536, 256, 0, stream>>>(xb, wqb, bqkv, qo, ko, vto);
    attn_kernel<<<1024, 256, 0, stream>>>(qo, ko, vto, mb, ctx);
    out_gemm<<<512, 256, 0, stream>>>(ctx, wob, bo, out);
}

// Round 12
// 347.603 us; speedup vs baseline: 1.2122x; 1.0170x over previous
//
#include <hip/hip_runtime.h>
#include <stdint.h>

// Problem constants
#define B_ 4
#define S_ 2048
#define E_ 1024
#define H_ 16
#define HD_ 64

typedef __attribute__((ext_vector_type(8))) short bf16x8;    // 8 bf16 = 4 VGPRs (MFMA A/B frag)
typedef __attribute__((ext_vector_type(4))) float f32x4;     // 16x16 MFMA C/D frag
typedef __attribute__((ext_vector_type(16))) float f32x16;   // 32x32 MFMA C/D frag

__device__ __forceinline__ ushort f2b(float f) {
    union { float f; uint32_t u; } c; c.f = f;
    return (ushort)((c.u + 0x8000u) >> 16);   // round-to-nearest (ties up)
}

// truncating pack: two f32 -> {bf16_trunc(a) lo, bf16_trunc(b) hi} in ONE v_perm.
// Used ONLY for P in attn: the same truncated P feeds numerator (PV) and
// denominator (ones-MFMA), so the <=2^-8 truncation bias cancels in the ratio.
__device__ __forceinline__ uint32_t pkbf_t(float a, float b) {
    union { float f; uint32_t u; } ca, cb; ca.f = a; cb.f = b;
#if __has_builtin(__builtin_amdgcn_perm)
    return __builtin_amdgcn_perm(cb.u, ca.u, 0x07060302u);
#else
    return (ca.u >> 16) | (cb.u & 0xFFFF0000u);
#endif
}

// all-ones iff bit `pos` of wn is set (1 op: v_bfe_i32)
__device__ __forceinline__ uint32_t keepmask(uint32_t wn, int pos) {
#if __has_builtin(__builtin_amdgcn_sbfe)
    return (uint32_t)__builtin_amdgcn_sbfe((int)wn, pos, 1);
#else
    return (uint32_t)(((int32_t)(wn << (31 - pos))) >> 31);
#endif
}

#if __has_builtin(__builtin_amdgcn_exp2f)
#define EXP2(x) __builtin_amdgcn_exp2f(x)
#else
#define EXP2(x) exp2f(x)
#endif

// async global->LDS, 16B per lane; LDS dest = wave-uniform base + lane*16,
// global src = PER-LANE address (gather) -> source-side permutations are free.
__device__ __forceinline__ void gl2lds16(const ushort* g, const ushort* l) {
    __builtin_amdgcn_global_load_lds(
        (const __attribute__((address_space(1))) unsigned int*)g,
        (__attribute__((address_space(3))) unsigned int*)l,
        16, 0, 0);
}

// ---------------------------------------------------------------- fused converts
__global__ __launch_bounds__(256) void cvt_all(
    const float* __restrict__ x, const float* __restrict__ wq, const float* __restrict__ wo,
    ushort* __restrict__ xb, ushort* __restrict__ wqb, ushort* __restrict__ wob) {
    int i = blockIdx.x * 256 + threadIdx.x;
    const float* src; ushort* dst; int off;
    if (i < 2097152)      { src = x;  dst = xb;  off = i; }
    else if (i < 2883584) { src = wq; dst = wqb; off = i - 2097152; }
    else                  { src = wo; dst = wob; off = i - 2883584; }
    float4 f = ((const float4*)src)[off];
    ushort4 o;
    o.x = f2b(f.x); o.y = f2b(f.y); o.z = f2b(f.z); o.w = f2b(f.w);
    ((ushort4*)dst)[off] = o;
}

// mask [B,S,S] int32 (0/1) -> bit-packed, kt-major:
// mb[((b*32 + kt)*2048 + q)*2 + w] bit c = mask[b][q][kt*64 + w*32 + c]
__global__ __launch_bounds__(256) void pack_mask(const int* __restrict__ mask,
                                                 uint32_t* __restrict__ mb) {
    int i = blockIdx.x * 256 + threadIdx.x;   // 16777216 threads
    unsigned long long bal = __ballot(mask[i] == 1);
    int lane = threadIdx.x & 63;
    if (lane < 2) {
        int b = i >> 22, q = (i >> 11) & 2047, c = i & 2047;
        int kt = c >> 6;
        mb[((uint64_t)(b * 32 + kt) * 2048 + q) * 2 + lane] =
            (lane == 0) ? (uint32_t)bal : (uint32_t)(bal >> 32);
    }
}

// ---------------------------------------------------------------- GEMM core (dist-2 ring, 32x32x16, T2-swizzled LDS)
// Validated round 10: swizzle dropped SQ_LDS_BANK_CONFLICT (qkv fell out of
// top-5, 96.4 -> <92.6 us). Unchanged.
template <int KD>
__device__ __forceinline__ void gemm_bt_core(
    const ushort* __restrict__ A, const ushort* __restrict__ Bm,
    int m0, int n0, ushort* L, f32x16 (&acc)[2][2])
{
    constexpr int NST = KD / 32;
    const int tid  = threadIdx.x;
    const int lane = tid & 63;
    const int wave = tid >> 6;
    const int wm = wave >> 1, wn = wave & 1;
    const int fr = lane & 31;            // row/col within 32x32 tile
    const int fq = lane >> 5;            // k-half selector
    const int fsw = (lane >> 1) & 3;     // row bits 1-2 (read-side swizzle)
    const int lrow = lane >> 2;
    const int lk   = (((lane & 3) ^ ((lane >> 3) & 3)) * 8);  // swizzled source k-chunk

#pragma unroll
    for (int i = 0; i < 2; ++i)
#pragma unroll
        for (int j = 0; j < 2; ++j)
#pragma unroll
            for (int e = 0; e < 16; ++e) acc[i][j][e] = 0.f;

    ushort* s0 = L;
    ushort* s1 = L + 8192;
    ushort* s2 = L + 16384;

    const uint64_t arow = (uint64_t)(m0 + lrow) * KD + lk;
    const uint64_t brow = (uint64_t)(n0 + lrow) * KD + lk;

#define GEMM_STAGE(k0, slot)                                                     \
    {                                                                            \
        _Pragma("unroll")                                                        \
        for (int t = 0; t < 2; ++t) {                                            \
            const int r0 = t * 64 + wave * 16;                                   \
            gl2lds16(&A [arow + (uint64_t)r0 * KD + (k0)], &(slot)[r0 * 32]);    \
            gl2lds16(&Bm[brow + (uint64_t)r0 * KD + (k0)], &(slot)[4096 + r0 * 32]); \
        }                                                                        \
    }

    GEMM_STAGE(0, s0);
    GEMM_STAGE(32, s1);
    asm volatile("s_waitcnt vmcnt(4)" ::: "memory");
    __builtin_amdgcn_s_barrier();
    __builtin_amdgcn_sched_barrier(0);

    ushort* cur = s0; ushort* nxt = s1; ushort* tgt = s2;

    for (int kt = 0; kt < NST; ++kt) {
        if (kt < NST - 2) GEMM_STAGE((kt + 2) * 32, tgt);

        bf16x8 af[2][2], bfr[2][2];      // [tile i|j][k-subtile s]
#pragma unroll
        for (int i = 0; i < 2; ++i)
#pragma unroll
            for (int s = 0; s < 2; ++s)
                af[i][s] = *(const bf16x8*)&cur[(wm * 64 + i * 32 + fr) * 32 +
                                                 (((s * 2 + fq) ^ fsw) * 8)];
#pragma unroll
        for (int j = 0; j < 2; ++j)
#pragma unroll
            for (int s = 0; s < 2; ++s)
                bfr[j][s] = *(const bf16x8*)&cur[4096 + (wn * 64 + j * 32 + fr) * 32 +
                                                  (((s * 2 + fq) ^ fsw) * 8)];
        __builtin_amdgcn_s_setprio(1);
#pragma unroll
        for (int s = 0; s < 2; ++s)
#pragma unroll
            for (int i = 0; i < 2; ++i)
#pragma unroll
                for (int j = 0; j < 2; ++j)
                    acc[i][j] = __builtin_amdgcn_mfma_f32_32x32x16_bf16(
                        af[i][s], bfr[j][s], acc[i][j], 0, 0, 0);
        __builtin_amdgcn_s_setprio(0);

        if (kt < NST - 2) {
            asm volatile("s_waitcnt vmcnt(4)" ::: "memory");
        } else {
            asm volatile("s_waitcnt vmcnt(0)" ::: "memory");
        }
        __builtin_amdgcn_s_barrier();
        __builtin_amdgcn_sched_barrier(0);

        ushort* o = cur; cur = nxt; nxt = tgt; tgt = o;
    }
#undef GEMM_STAGE
}

// ---------------------------------------------------------------- QKV GEMM
__global__ __launch_bounds__(256) void qkv_gemm(
    const ushort* __restrict__ xb, const ushort* __restrict__ wb,
    const float* __restrict__ bqkv,
    ushort* __restrict__ qo, ushort* __restrict__ ko, ushort* __restrict__ vto)
{
    __shared__ __align__(16) ushort L[24576];   // 48 KB ring
    f32x16 acc[2][2];
    const int lin = blockIdx.x;                  // 1536 = 8 * 192
    const int swz = (lin & 7) * 192 + (lin >> 3);
    const int m0 = (swz & 63) * 128;
    const int n0 = (swz >> 6) * 128;
    gemm_bt_core<1024>(xb, wb, m0, n0, L, acc);

    const int lane = threadIdx.x & 63, wave = threadIdx.x >> 6;
    const int wm = wave >> 1, wn = wave & 1;
    const int ls = lane >> 5;                    // k-group half
    const float QSC = 0.125f * 1.4426950408889634f;
#pragma unroll
    for (int j = 0; j < 2; ++j) {
        const int n = n0 + wn * 64 + j * 32 + (lane & 31);
        const int h = n / 192, f = n % 192;
        const float bias = bqkv[n];
#pragma unroll
        for (int i2 = 0; i2 < 2; ++i2) {
#pragma unroll
            for (int q = 0; q < 4; ++q) {
                const int mbase = m0 + wm * 64 + i2 * 32 + q * 8 + ls * 4;
                if (f < 128) {
#pragma unroll
                    for (int v = 0; v < 4; ++v) {
                        const int m = mbase + v;
                        const int b = m >> 11, s = m & 2047;
                        const float val = acc[i2][j][q * 4 + v] + bias;
                        if (f < 64) qo[((uint64_t)(b * 16 + h) * 2048 + s) * 64 + f]        = f2b(val * QSC);
                        else        ko[((uint64_t)(b * 16 + h) * 2048 + s) * 64 + (f - 64)] = f2b(val);
                    }
                } else {
                    const int b = mbase >> 11, s = mbase & 2047;
                    ushort4 pk;
                    pk.x = f2b(acc[i2][j][q * 4 + 0] + bias);
                    pk.y = f2b(acc[i2][j][q * 4 + 1] + bias);
                    pk.z = f2b(acc[i2][j][q * 4 + 2] + bias);
                    pk.w = f2b(acc[i2][j][q * 4 + 3] + bias);
                    *(ushort4*)&vto[((uint64_t)(b * 16 + h) * 64 + (f - 128)) * 2048 + s] = pk;
                }
            }
        }
    }
}

// ---------------------------------------------------------------- flash attention v13
// = v11 structure (3-slot dist-2 ring, counted vmcnt; validated 92.7 us) with
//   QBLK 128 -> 256: each block handles 2 q-tiles (64 q-rows/wave, i=0..3).
//   Grid 1024 -> 512 = 2 blocks/CU -> ALL blocks co-resident, ZERO tail (the
//   25% tail at 3/CU was the visible stall). K/V staging per phase unchanged
//   (shared by both q-halves) -> staging + barriers per unit work HALVE.
//   Per-phase vmem = 4 gl2lds + 4 mask loads -> vmcnt(8).
//   VGPR: ~230 worst-case live, fits 256-budget at 2 waves/SIMD
//   (launch_bounds(256,2)). Spill signature = WRITE_SIZE blowup (rule #20).
__global__ __launch_bounds__(256, 2) void attn_kernel(
    const ushort* __restrict__ qa, const ushort* __restrict__ ka,
    const ushort* __restrict__ vta, const uint32_t* __restrict__ mbits,
    ushort* __restrict__ ctxo)
{
    __shared__ __align__(16) ushort LDSH[24576];   // 48 KB: 3 x (K 8KB + V 8KB)
    ushort* const Ks0 = LDSH;
    ushort* const Vt0 = LDSH + 4096;
    ushort* const Ks1 = LDSH + 8192;
    ushort* const Vt1 = LDSH + 12288;
    ushort* const Ks2 = LDSH + 16384;
    ushort* const Vt2 = LDSH + 20480;
    ushort* const CTX = LDSH;                      // 32 KB epilogue stage (all slots dead)

    // bijective XCD swizzle for 512 = 8 XCDs x (8 bh x 8 qb):
    // xcd = bid&7 owns bh in {xcd*8 .. xcd*8+7}, 8 q-blocks each.
    const int bid = blockIdx.x;
    const int bh = (bid & 7) * 8 + (bid >> 6);
    const int qb = (bid >> 3) & 7;                 // 256-row q-block
    const int b = bh >> 4;
    const int tid = threadIdx.x, lane = tid & 63, wave = tid >> 6;
    const int col = lane & 15, rg = lane >> 4;

    const uint64_t bhoff = (uint64_t)bh * (S_ * 64);
    const ushort* qp = qa + bhoff + (uint64_t)qb * 256 * 64;
    const ushort* kp = ka + bhoff;
    const ushort* vp = vta + bhoff;                       // [64][2048]
    // mask words for this thread's 4 q-rows (i=0..3 -> +i*32 words)
    const uint32_t* mkb = mbits + ((uint64_t)(b * 32) * 2048 + qb * 256 + wave * 64 + col) * 2;

    const int lr = lane >> 3;
    const int usw = (lane & 7) ^ lr;
    const int r0s = wave * 16 + lr;
    const int r1s = r0s + 8;
    const int sg0 = (r0s & 32) | ((r0s & 12) << 1) | ((r0s & 16) >> 2) | (r0s & 3);
    const int sg1 = (r1s & 32) | ((r1s & 12) << 1) | ((r1s & 16) >> 2) | (r1s & 3);
    const int kb0 = sg0 * 64 + usw * 8;
    const int kb1 = sg1 * 64 + usw * 8;
    const int vb0 = r0s * 2048 + usw * 8;
    const int vb1 = r1s * 2048 + usw * 8;
    const int ldst0 = wave * 1024;
    const int ldst1 = ldst0 + 512;

    // Q fragments straight from global (4 x 16 q-rows per wave)
    bf16x8 aq[4][2];
#pragma unroll
    for (int i = 0; i < 4; ++i)
#pragma unroll
        for (int k2 = 0; k2 < 2; ++k2)
            aq[i][k2] = *(const bf16x8*)&qp[(wave * 64 + i * 16 + col) * 64 + k2 * 32 + rg * 8];

    gl2lds16(&kp[kb0], &Ks0[ldst0]);
    gl2lds16(&kp[kb1], &Ks0[ldst1]);
    gl2lds16(&vp[vb0], &Vt0[ldst0]);
    gl2lds16(&vp[vb1], &Vt0[ldst1]);
    gl2lds16(&kp[4096 + kb0], &Ks1[ldst0]);
    gl2lds16(&kp[4096 + kb1], &Ks1[ldst1]);
    gl2lds16(&vp[vb0 + 64], &Vt1[ldst0]);
    gl2lds16(&vp[vb1 + 64], &Vt1[ldst1]);
    uint2 m_cur[4], m_nxt[4], m_new[4];
#pragma unroll
    for (int i = 0; i < 4; ++i) {
        m_cur[i] = *(const uint2*)(mkb + i * 32);
        m_nxt[i] = *(const uint2*)(mkb + 4096 + i * 32);
        m_new[i] = m_nxt[i];
    }
    asm volatile("s_waitcnt vmcnt(0)" ::: "memory");
    __builtin_amdgcn_s_barrier();
    __builtin_amdgcn_sched_barrier(0);

    const f32x4 fz = {0.f, 0.f, 0.f, 0.f};
    f32x4 acc[4][4];                      // ctx^T: [dt][i]
#pragma unroll
    for (int dt = 0; dt < 4; ++dt)
#pragma unroll
        for (int i = 0; i < 4; ++i) acc[dt][i] = fz;
    f32x4 acc5[4] = {fz, fz, fz, fz};

    bf16x8 vone;
#pragma unroll
    for (int e = 0; e < 8; ++e) vone[e] = (short)0x3F80;

    int bpos[2][4];
#pragma unroll
    for (int p = 0; p < 2; ++p)
#pragma unroll
        for (int v = 0; v < 4; ++v) bpos[p][v] = rg * 8 + p * 4 + v;

    const int u0 = (rg ^ (col & 7)) << 3;

    const ushort* cK = Ks0; const ushort* cV = Vt0;
    const ushort* nK = Ks1; const ushort* nV = Vt1;
    ushort* tK = Ks2; ushort* tV = Vt2;

    for (int kt = 0; kt < 32; ++kt) {
        // prefetch kt+2 (distance 2): 4 gl2lds + 4 mask loads = 8 vmem ops
        if (kt < 30) {
            const int k2 = (kt + 2) * 4096;
            gl2lds16(&kp[k2 + kb0], &tK[ldst0]);
            gl2lds16(&kp[k2 + kb1], &tK[ldst1]);
            gl2lds16(&vp[vb0 + (kt + 2) * 64], &tV[ldst0]);
            gl2lds16(&vp[vb1 + (kt + 2) * 64], &tV[ldst1]);
#pragma unroll
            for (int i = 0; i < 4; ++i)
                m_new[i] = *(const uint2*)(mkb + (uint64_t)(kt + 2) * 4096 + i * 32);
        }

        // scores S^T (log2 domain): 32 MFMA
        f32x4 sc[4][4];
        __builtin_amdgcn_s_setprio(1);
#pragma unroll
        for (int j = 0; j < 4; ++j) {
            bf16x8 bk0 = *(const bf16x8*)&cK[(j * 16 + col) * 64 + u0];
            bf16x8 bk1 = *(const bf16x8*)&cK[(j * 16 + col) * 64 + (u0 ^ 32)];
#pragma unroll
            for (int i = 0; i < 4; ++i) {
                f32x4 z = __builtin_amdgcn_mfma_f32_16x16x32_bf16(bk0, aq[i][0], fz, 0, 0, 0);
                sc[i][j] = __builtin_amdgcn_mfma_f32_16x16x32_bf16(bk1, aq[i][1], z, 0, 0, 0);
            }
        }
        __builtin_amdgcn_s_setprio(0);

        // mask + exp2 (thinned) -> P fragments
        bf16x8 bp[4][2];
#pragma unroll
        for (int i = 0; i < 4; ++i) {
            const uint2 mw = m_cur[i];
            const uint32_t wnx = ~mw.x, wny = ~mw.y;
            union { uint32_t w[4]; bf16x8 v; } p0, p1;
#pragma unroll
            for (int j = 0; j < 4; ++j) {
                const uint32_t wn = (j & 2) ? wny : wnx;
                const int p = j & 1;
                float pe[4];
#pragma unroll
                for (int v = 0; v < 4; ++v) {
                    union { float f; uint32_t u; } cu;
                    cu.f = sc[i][j][v];
                    cu.u &= keepmask(wn, bpos[p][v]);
                    pe[v] = EXP2(cu.f);
                }
                const uint32_t lo = pkbf_t(pe[0], pe[1]);
                const uint32_t hi = pkbf_t(pe[2], pe[3]);
                if (j < 2) { p0.w[p * 2] = lo; p0.w[p * 2 + 1] = hi; }
                else       { p1.w[p * 2] = lo; p1.w[p * 2 + 1] = hi; }
            }
            bp[i][0] = p0.v;
            bp[i][1] = p1.v;
        }

        // PV + denominator: 40 MFMA
        __builtin_amdgcn_s_setprio(1);
#pragma unroll
        for (int i = 0; i < 4; ++i) {
            acc5[i] = __builtin_amdgcn_mfma_f32_16x16x32_bf16(vone, bp[i][0], acc5[i], 0, 0, 0);
            acc5[i] = __builtin_amdgcn_mfma_f32_16x16x32_bf16(vone, bp[i][1], acc5[i], 0, 0, 0);
        }
#pragma unroll
        for (int dt = 0; dt < 4; ++dt) {
            bf16x8 av0 = *(const bf16x8*)&cV[(dt * 16 + col) * 64 + u0];
            bf16x8 av1 = *(const bf16x8*)&cV[(dt * 16 + col) * 64 + (u0 ^ 32)];
#pragma unroll
            for (int i = 0; i < 4; ++i) {
                acc[dt][i] = __builtin_amdgcn_mfma_f32_16x16x32_bf16(av0, bp[i][0], acc[dt][i], 0, 0, 0);
                acc[dt][i] = __builtin_amdgcn_mfma_f32_16x16x32_bf16(av1, bp[i][1], acc[dt][i], 0, 0, 0);
            }
        }
        __builtin_amdgcn_s_setprio(0);

        // counted-vmcnt barrier: keep THIS phase's 8 prefetch ops in flight.
        if (kt < 30) {
            asm volatile("s_waitcnt vmcnt(8)" ::: "memory");
        } else {
            asm volatile("s_waitcnt vmcnt(0)" ::: "memory");
        }
        __builtin_amdgcn_s_barrier();
        __builtin_amdgcn_sched_barrier(0);

        const ushort* oK = cK; const ushort* oV = cV;
        cK = nK; cV = nV; nK = tK; nV = tV; tK = (ushort*)oK; tV = (ushort*)oV;
#pragma unroll
        for (int i = 0; i < 4; ++i) { m_cur[i] = m_nxt[i]; m_nxt[i] = m_new[i]; }
    }

    float linv[4];
#pragma unroll
    for (int i = 0; i < 4; ++i) linv[i] = 1.0f / acc5[i][0];

    // transpose ctx^T through CTX (32 KB, swizzled) for coalesced store
#pragma unroll
    for (int dt = 0; dt < 4; ++dt)
#pragma unroll
        for (int i = 0; i < 4; ++i) {
            const int q = wave * 64 + i * 16 + col;
            const int d = dt * 16 + rg * 4;
            const int gg = (d >> 3) ^ (q & 7);
            ushort4 pk;
            pk.x = f2b(acc[dt][i][0] * linv[i]);
            pk.y = f2b(acc[dt][i][1] * linv[i]);
            pk.z = f2b(acc[dt][i][2] * linv[i]);
            pk.w = f2b(acc[dt][i][3] * linv[i]);
            *(ushort4*)&CTX[q * 64 + gg * 8 + (d & 7)] = pk;
        }
    __syncthreads();
    const int h = bh & 15;
    const uint64_t obase = (uint64_t)(b * S_ + qb * 256) * E_ + (uint64_t)h * 64;
#pragma unroll
    for (int t4 = 0; t4 < 8; ++t4) {
        const int id = tid + t4 * 256;
        const int r = id >> 3, c8 = id & 7;
        *(bf16x8*)&ctxo[obase + (uint64_t)r * E_ + c8 * 8] =
            *(const bf16x8*)&CTX[r * 64 + ((c8 ^ (r & 7)) << 3)];
    }
}

// ---------------------------------------------------------------- output GEMM
__global__ __launch_bounds__(256) void out_gemm(
    const ushort* __restrict__ ctxb, const ushort* __restrict__ wob,
    const float* __restrict__ bo, float* __restrict__ out)
{
    __shared__ __align__(16) ushort L[24576];   // 48 KB ring
    f32x16 acc[2][2];
    const int lin = blockIdx.x;
    const int swz = (lin & 7) * 64 + (lin >> 3);
    const int m0 = (swz & 63) * 128;
    const int n0 = (swz >> 6) * 128;
    gemm_bt_core<1024>(ctxb, wob, m0, n0, L, acc);

    const int lane = threadIdx.x & 63, wave = threadIdx.x >> 6;
    const int wm = wave >> 1, wn = wave & 1;
    const int ls = lane >> 5;
#pragma unroll
    for (int j = 0; j < 2; ++j) {
        const int n = n0 + wn * 64 + j * 32 + (lane & 31);
        const float bias = bo[n];
#pragma unroll
        for (int i2 = 0; i2 < 2; ++i2) {
#pragma unroll
            for (int q = 0; q < 4; ++q) {
                const int mbase = m0 + wm * 64 + i2 * 32 + q * 8 + ls * 4;
#pragma unroll
                for (int v = 0; v < 4; ++v)
                    out[(uint64_t)(mbase + v) * 1024 + n] = acc[i2][j][q * 4 + v] + bias;
            }
        }
    }
}

// ---------------------------------------------------------------- launch
extern "C" void kernel_launch(void* const* d_in, const int* in_sizes, int n_in,
                              void* d_out, int out_size, void* d_ws, size_t ws_size,
                              hipStream_t stream)
{
    const float* x    = (const float*)d_in[0];
    const int*   mask = (const int*)d_in[1];
    const float* Wqkv = (const float*)d_in[2];
    const float* bqkv = (const float*)d_in[3];
    const float* Wo   = (const float*)d_in[4];
    const float* bo   = (const float*)d_in[5];
    float* out = (float*)d_out;

    char* p = (char*)d_ws;
    ushort* xb  = (ushort*)p; p += (size_t)8388608 * 2;   // x bf16 [8192][1024]
    ushort* wqb = (ushort*)p; p += (size_t)3145728 * 2;   // Wqkv bf16 [3072][1024]
    ushort* wob = (ushort*)p; p += (size_t)1048576 * 2;   // Wo bf16 [1024][1024]
    ushort* qo  = (ushort*)p; p += (size_t)8388608 * 2;   // Q bf16 (log2-domain prescale)
    ushort* ko  = (ushort*)p; p += (size_t)8388608 * 2;   // K bf16 [bh][s][64]
    ushort* vto = (ushort*)p; p += (size_t)8388608 * 2;   // V^T bf16 [bh][64][s]
    ushort* ctx = (ushort*)p; p += (size_t)8388608 * 2;   // ctx bf16 [8192][1024]
    uint32_t* mb = (uint32_t*)p;                          // packed mask bits (kt-major), 2 MB

    cvt_all<<<12288, 256, 0, stream>>>(x, Wqkv, Wo, xb, wqb, wob);
    pack_mask<<<65536, 256, 0, stream>>>(mask, mb);
    qkv_gemm<<<1536, 256, 0, stream>>>(xb, wqb, bqkv, qo, ko, vto);
    attn_kernel<<<512, 256, 0, stream>>>(qo, ko, vto, mb, ctx);
    out_gemm<<<512, 256, 0, stream>>>(ctx, wob, bo, out);
}